// Round 3
// baseline (218.436 us; speedup 1.0000x reference)
//
#include <hip/hip_runtime.h>
#include <hip/hip_bf16.h>
#include <math.h>

#define N_TOK 2048
#define FEAT  768
#define HEADS 12
#define DHEAD 64
#define SPLIT 4
#define KV_PER (N_TOK / SPLIT)

typedef __bf16 v8bf __attribute__((ext_vector_type(8)));
typedef __bf16 v4bf __attribute__((ext_vector_type(4)));
typedef float  v4f  __attribute__((ext_vector_type(4)));

#define XE ((size_t)N_TOK * FEAT)   // 1572864
#define WE ((size_t)FEAT * FEAT)    //  589824
#define QKV_LD (3 * FEAT)           // 2304

// fold (1/sqrt(64)) * log2(e) into Wq so softmax is a bare exp2
#define SCALE_FOLD 0.18033688011112042f

// ---------------------------------------------------------------- convert (1 launch)
__global__ __launch_bounds__(256) void cvt_all(
        const float* __restrict__ x,  const float* __restrict__ Wq,
        const float* __restrict__ Wk, const float* __restrict__ Wv,
        const float* __restrict__ Wo,
        __bf16* __restrict__ xb, __bf16* __restrict__ wqkv, __bf16* __restrict__ wob) {
    size_t i = ((size_t)blockIdx.x * 256 + threadIdx.x) * 4;
    const float* src; __bf16* dst; size_t off; float scale = 1.f;
    if (i < XE)               { src = x;  dst = xb;          off = i; }
    else if (i < XE + WE)     { src = Wq; dst = wqkv;        off = i - XE; scale = SCALE_FOLD; }
    else if (i < XE + 2 * WE) { src = Wk; dst = wqkv + WE;   off = i - XE - WE; }
    else if (i < XE + 3 * WE) { src = Wv; dst = wqkv + 2*WE; off = i - XE - 2*WE; }
    else                      { src = Wo; dst = wob;         off = i - XE - 3*WE; }
    float4 v = *(const float4*)(src + off);
    v4bf o;
    o[0] = (__bf16)(v.x * scale); o[1] = (__bf16)(v.y * scale);
    o[2] = (__bf16)(v.z * scale); o[3] = (__bf16)(v.w * scale);
    *(v4bf*)(dst + off) = o;
}

// ---------------------------------------------------------------- fused QKV GEMM, 128x128 tile
// C = x . [Wq'|Wk|Wv]^T.  Q,K parts -> qkv (row stride 2304, cols 0..1535).
// V part (blockIdx.x >= 12) -> vt transposed: vt[feature][token], feature = h*64+d.
__global__ __launch_bounds__(256) void gemm_qkv(
        const __bf16* __restrict__ A, const __bf16* __restrict__ B,
        __bf16* __restrict__ C, __bf16* __restrict__ vt) {
    __shared__ __bf16 As[128][40];
    __shared__ __bf16 Bs[128][40];
    const int t    = threadIdx.x;
    const int lane = t & 63, w = t >> 6;
    const int quad = lane >> 4, l15 = lane & 15;
    const int wm = w & 1, wn = w >> 1;
    const int bm = blockIdx.y * 128, bn = blockIdx.x * 128;
    const int r0 = t >> 2, c0 = (t & 3) * 8;

    v4f acc[4][4] = {};
    for (int k0 = 0; k0 < FEAT; k0 += 32) {
        *(float4*)&As[r0     ][c0] = *(const float4*)(A + (size_t)(bm + r0     ) * FEAT + k0 + c0);
        *(float4*)&As[r0 + 64][c0] = *(const float4*)(A + (size_t)(bm + r0 + 64) * FEAT + k0 + c0);
        *(float4*)&Bs[r0     ][c0] = *(const float4*)(B + (size_t)(bn + r0     ) * FEAT + k0 + c0);
        *(float4*)&Bs[r0 + 64][c0] = *(const float4*)(B + (size_t)(bn + r0 + 64) * FEAT + k0 + c0);
        __syncthreads();
        v8bf a[4], b[4];
#pragma unroll
        for (int mi = 0; mi < 4; mi++) a[mi] = *(const v8bf*)&As[wm * 64 + mi * 16 + l15][quad * 8];
#pragma unroll
        for (int ni = 0; ni < 4; ni++) b[ni] = *(const v8bf*)&Bs[wn * 64 + ni * 16 + l15][quad * 8];
#pragma unroll
        for (int mi = 0; mi < 4; mi++)
#pragma unroll
            for (int ni = 0; ni < 4; ni++)
                acc[mi][ni] = __builtin_amdgcn_mfma_f32_16x16x32_bf16(a[mi], b[ni], acc[mi][ni], 0, 0, 0);
        __syncthreads();
    }
    if (bn < 2 * FEAT) {         // Q,K region: normal row-major store
#pragma unroll
        for (int mi = 0; mi < 4; mi++)
#pragma unroll
            for (int ni = 0; ni < 4; ni++) {
                int col = bn + wn * 64 + ni * 16 + l15;
#pragma unroll
                for (int r = 0; r < 4; r++) {
                    int row = bm + wm * 64 + mi * 16 + quad * 4 + r;
                    C[(size_t)row * QKV_LD + col] = (__bf16)acc[mi][ni][r];
                }
            }
    } else {                     // V region: transposed packed store vt[col-1536][row]
#pragma unroll
        for (int mi = 0; mi < 4; mi++)
#pragma unroll
            for (int ni = 0; ni < 4; ni++) {
                int col = bn + wn * 64 + ni * 16 + l15 - 2 * FEAT;
                int row = bm + wm * 64 + mi * 16 + quad * 4;
                v4bf pk;
#pragma unroll
                for (int r = 0; r < 4; r++) pk[r] = (__bf16)acc[mi][ni][r];
                *(v4bf*)(vt + (size_t)col * N_TOK + row) = pk;
            }
    }
}

// ---------------------------------------------------------------- attention (barrier-free)
// QKV rows: [Q'|K] stride 2304 (Wq pre-scaled by 0.125*log2e). vt: [768][2048] V^T.
// Each wave owns 16 q-rows; P round-trip is intra-wave -> NO __syncthreads.
__global__ __launch_bounds__(256) void attention(
        const __bf16* __restrict__ QKV, const __bf16* __restrict__ vt,
        __bf16* __restrict__ Opart, float* __restrict__ lpart) {
    __shared__ __bf16 P[4][16][68];
    const int t    = threadIdx.x;
    const int lane = t & 63, w = t >> 6;
    const int quad = lane >> 4, l15 = lane & 15;
    const int h = blockIdx.y, s = blockIdx.z;
    const int q0 = blockIdx.x * 64;
    const int qrow = q0 + w * 16 + l15;

    const __bf16* qp = QKV + (size_t)qrow * QKV_LD + h * DHEAD + quad * 8;
    v8bf qf0 = *(const v8bf*)qp;
    v8bf qf1 = *(const v8bf*)(qp + 32);

    const __bf16* kbase = QKV + FEAT + h * DHEAD + quad * 8;
    const __bf16* vbase = vt + (size_t)(h * DHEAD + l15) * N_TOK + quad * 8;

    v4f o_acc[4] = {};
    float lacc[4] = {0.f, 0.f, 0.f, 0.f};

    for (int kv0 = s * KV_PER; kv0 < (s + 1) * KV_PER; kv0 += 64) {
        // ---- V B-frags: independent of the S chain, issue first
        v8bf vf[2][4];
#pragma unroll
        for (int ks = 0; ks < 2; ks++)
#pragma unroll
            for (int dt = 0; dt < 4; dt++)
                vf[ks][dt] = *(const v8bf*)(vbase + (size_t)dt * 16 * N_TOK + kv0 + ks * 32);
        // ---- S = Q' K^T
        v4f sv[4];
#pragma unroll
        for (int nt = 0; nt < 4; nt++) {
            const __bf16* kp = kbase + (size_t)(kv0 + nt * 16 + l15) * QKV_LD;
            v8bf kf0 = *(const v8bf*)kp;
            v8bf kf1 = *(const v8bf*)(kp + 32);
            v4f a = {};
            a = __builtin_amdgcn_mfma_f32_16x16x32_bf16(qf0, kf0, a, 0, 0, 0);
            a = __builtin_amdgcn_mfma_f32_16x16x32_bf16(qf1, kf1, a, 0, 0, 0);
            sv[nt] = a;
        }
        // ---- p = 2^s, row-sums per-lane (cross-lane reduce deferred)
        float pv[4][4];
#pragma unroll
        for (int r = 0; r < 4; r++) {
            float p0 = __builtin_amdgcn_exp2f(sv[0][r]);
            float p1 = __builtin_amdgcn_exp2f(sv[1][r]);
            float p2 = __builtin_amdgcn_exp2f(sv[2][r]);
            float p3 = __builtin_amdgcn_exp2f(sv[3][r]);
            pv[0][r] = p0; pv[1][r] = p1; pv[2][r] = p2; pv[3][r] = p3;
            lacc[r] += (p0 + p1) + (p2 + p3);
        }
        // ---- P to per-wave LDS region (intra-wave; compiler inserts lgkmcnt)
#pragma unroll
        for (int nt = 0; nt < 4; nt++)
#pragma unroll
            for (int r = 0; r < 4; r++)
                P[w][quad * 4 + r][nt * 16 + l15] = (__bf16)pv[nt][r];
        // ---- O += P V
#pragma unroll
        for (int ks = 0; ks < 2; ks++) {
            v8bf pa = *(const v8bf*)&P[w][l15][ks * 32 + quad * 8];
#pragma unroll
            for (int dt = 0; dt < 4; dt++)
                o_acc[dt] = __builtin_amdgcn_mfma_f32_16x16x32_bf16(pa, vf[ks][dt], o_acc[dt], 0, 0, 0);
        }
    }
    // ---- epilogue: reduce l across 16 col-lanes; store normalized bf16 partial + l
    __bf16* op = Opart + (size_t)s * XE;
#pragma unroll
    for (int r = 0; r < 4; r++) {
        float l = lacc[r];
        l += __shfl_xor(l, 1); l += __shfl_xor(l, 2);
        l += __shfl_xor(l, 4); l += __shfl_xor(l, 8);
        float linv = 1.0f / l;
        int row = q0 + w * 16 + quad * 4 + r;
        if (l15 == 0) lpart[((size_t)s * HEADS + h) * N_TOK + row] = l;
#pragma unroll
        for (int dt = 0; dt < 4; dt++)
            op[(size_t)row * FEAT + h * DHEAD + dt * 16 + l15] = (__bf16)(o_acc[dt][r] * linv);
    }
}

// ---------------------------------------------------------------- combine split partials
__global__ __launch_bounds__(256) void combine(
        const __bf16* __restrict__ Op, const float* __restrict__ lp, __bf16* __restrict__ Ob) {
    size_t i = ((size_t)blockIdx.x * 256 + threadIdx.x) * 4;
    int row = (int)(i / FEAT), col = (int)(i % FEAT), h = col >> 6;
    float ls[SPLIT], tot = 0.f;
#pragma unroll
    for (int s = 0; s < SPLIT; s++) {
        ls[s] = lp[((size_t)s * HEADS + h) * N_TOK + row];
        tot += ls[s];
    }
    float inv = 1.0f / tot;
    float a0 = 0.f, a1 = 0.f, a2 = 0.f, a3 = 0.f;
#pragma unroll
    for (int s = 0; s < SPLIT; s++) {
        v4bf p = *(const v4bf*)(Op + s * XE + i);
        float wgt = ls[s] * inv;
        a0 += wgt * (float)p[0]; a1 += wgt * (float)p[1];
        a2 += wgt * (float)p[2]; a3 += wgt * (float)p[3];
    }
    v4bf o;
    o[0] = (__bf16)a0; o[1] = (__bf16)a1; o[2] = (__bf16)a2; o[3] = (__bf16)a3;
    *(v4bf*)(Ob + i) = o;
}

// ---------------------------------------------------------------- output proj + residual, 128x128 tile
__global__ __launch_bounds__(256) void gemm_out(
        const __bf16* __restrict__ A, const __bf16* __restrict__ B,
        float* __restrict__ Cf, const float* __restrict__ resid) {
    __shared__ __bf16 As[128][40];
    __shared__ __bf16 Bs[128][40];
    const int t    = threadIdx.x;
    const int lane = t & 63, w = t >> 6;
    const int quad = lane >> 4, l15 = lane & 15;
    const int wm = w & 1, wn = w >> 1;
    const int bm = blockIdx.y * 128, bn = blockIdx.x * 128;
    const int r0 = t >> 2, c0 = (t & 3) * 8;

    v4f acc[4][4] = {};
    for (int k0 = 0; k0 < FEAT; k0 += 32) {
        *(float4*)&As[r0     ][c0] = *(const float4*)(A + (size_t)(bm + r0     ) * FEAT + k0 + c0);
        *(float4*)&As[r0 + 64][c0] = *(const float4*)(A + (size_t)(bm + r0 + 64) * FEAT + k0 + c0);
        *(float4*)&Bs[r0     ][c0] = *(const float4*)(B + (size_t)(bn + r0     ) * FEAT + k0 + c0);
        *(float4*)&Bs[r0 + 64][c0] = *(const float4*)(B + (size_t)(bn + r0 + 64) * FEAT + k0 + c0);
        __syncthreads();
        v8bf a[4], b[4];
#pragma unroll
        for (int mi = 0; mi < 4; mi++) a[mi] = *(const v8bf*)&As[wm * 64 + mi * 16 + l15][quad * 8];
#pragma unroll
        for (int ni = 0; ni < 4; ni++) b[ni] = *(const v8bf*)&Bs[wn * 64 + ni * 16 + l15][quad * 8];
#pragma unroll
        for (int mi = 0; mi < 4; mi++)
#pragma unroll
            for (int ni = 0; ni < 4; ni++)
                acc[mi][ni] = __builtin_amdgcn_mfma_f32_16x16x32_bf16(a[mi], b[ni], acc[mi][ni], 0, 0, 0);
        __syncthreads();
    }
#pragma unroll
    for (int mi = 0; mi < 4; mi++)
#pragma unroll
        for (int ni = 0; ni < 4; ni++) {
            int col = bn + wn * 64 + ni * 16 + l15;
#pragma unroll
            for (int r = 0; r < 4; r++) {
                int row = bm + wm * 64 + mi * 16 + quad * 4 + r;
                Cf[(size_t)row * FEAT + col] = acc[mi][ni][r] + resid[(size_t)row * FEAT + col];
            }
        }
}

// ---------------------------------------------------------------- layernorm
__global__ __launch_bounds__(256) void ln_kernel(
        const float* __restrict__ Y, const float* __restrict__ gamma,
        const float* __restrict__ beta, float* __restrict__ out) {
    __shared__ float sbuf[4];
    const int row = blockIdx.x, t = threadIdx.x;
    const float* y = Y + (size_t)row * FEAT;
    float v0 = y[t], v1 = y[t + 256], v2 = y[t + 512];
    float s = v0 + v1 + v2;
#pragma unroll
    for (int m = 32; m; m >>= 1) s += __shfl_xor(s, m);
    if ((t & 63) == 0) sbuf[t >> 6] = s;
    __syncthreads();
    float mean = (sbuf[0] + sbuf[1] + sbuf[2] + sbuf[3]) * (1.f / FEAT);
    __syncthreads();
    float d0 = v0 - mean, d1 = v1 - mean, d2 = v2 - mean;
    float q = d0 * d0 + d1 * d1 + d2 * d2;
#pragma unroll
    for (int m = 32; m; m >>= 1) q += __shfl_xor(q, m);
    if ((t & 63) == 0) sbuf[t >> 6] = q;
    __syncthreads();
    float var = (sbuf[0] + sbuf[1] + sbuf[2] + sbuf[3]) * (1.f / FEAT);
    float rs = rsqrtf(var + 1e-12f);
    float* o = out + (size_t)row * FEAT;
    o[t]       = d0 * rs * gamma[t]       + beta[t];
    o[t + 256] = d1 * rs * gamma[t + 256] + beta[t + 256];
    o[t + 512] = d2 * rs * gamma[t + 512] + beta[t + 512];
}

// ---------------------------------------------------------------- launch
extern "C" void kernel_launch(void* const* d_in, const int* in_sizes, int n_in,
                              void* d_out, int out_size, void* d_ws, size_t ws_size,
                              hipStream_t stream) {
    const float* x     = (const float*)d_in[0];
    const float* Wq    = (const float*)d_in[1];
    const float* Wk    = (const float*)d_in[2];
    const float* Wv    = (const float*)d_in[3];
    const float* Wo    = (const float*)d_in[4];
    const float* gamma = (const float*)d_in[5];
    const float* beta  = (const float*)d_in[6];
    float* out = (float*)d_out;

    char* ws = (char*)d_ws;
    size_t off = 0;
    auto alloc = [&](size_t bytes) -> void* {
        void* p = ws + off;
        off += (bytes + 255) & ~(size_t)255;
        return p;
    };
    __bf16* xb   = (__bf16*)alloc(XE * 2);            // dead after gemm_qkv
    __bf16* wqkv = (__bf16*)alloc(3 * WE * 2);        // dead after gemm_qkv
    __bf16* wob  = (__bf16*)alloc(WE * 2);
    __bf16* qkv  = (__bf16*)alloc(XE * 3 * 2);        // [Q'|K|(unused V)] stride 2304
    __bf16* vtb  = (__bf16*)alloc((size_t)FEAT * N_TOK * 2);   // V^T [768][2048]
    __bf16* Ob   = (__bf16*)alloc(XE * 2);
    __bf16* Op   = (__bf16*)alloc(SPLIT * XE * 2);    // normalized split partials
    float*  lp   = (float*)alloc(SPLIT * HEADS * N_TOK * 4);
    float*  Yf   = (float*)ws;                        // aliases xb+wqkv (dead by gemm_out)

    cvt_all<<<(int)((XE + 4 * WE) / 4 / 256), 256, 0, stream>>>(x, Wq, Wk, Wv, Wo, xb, wqkv, wob);

    gemm_qkv<<<dim3(QKV_LD / 128, N_TOK / 128), 256, 0, stream>>>(xb, wqkv, qkv, vtb);

    attention<<<dim3(N_TOK / 64, HEADS, SPLIT), 256, 0, stream>>>(qkv, vtb, Op, lp);

    combine<<<(int)(XE / 4 / 256), 256, 0, stream>>>(Op, lp, Ob);

    gemm_out<<<dim3(FEAT / 128, N_TOK / 128), 256, 0, stream>>>(Ob, wob, Yf, x);

    ln_kernel<<<N_TOK, 256, 0, stream>>>(Yf, gamma, beta, out);
}

// Round 4
// 183.958 us; speedup vs baseline: 1.1874x; 1.1874x over previous
//
#include <hip/hip_runtime.h>
#include <hip/hip_bf16.h>
#include <math.h>

#define N_TOK 2048
#define FEAT  768
#define HEADS 12
#define DHEAD 64
#define SPLIT 4
#define KV_PER (N_TOK / SPLIT)

typedef __bf16 v8bf __attribute__((ext_vector_type(8)));
typedef __bf16 v4bf __attribute__((ext_vector_type(4)));
typedef float  v4f  __attribute__((ext_vector_type(4)));

#define XE ((size_t)N_TOK * FEAT)   // 1572864
#define WE ((size_t)FEAT * FEAT)    //  589824
#define QKV_LD (3 * FEAT)           // 2304

// fold (1/sqrt(64)) * log2(e) into Wq so softmax is a bare exp2
#define SCALE_FOLD 0.18033688011112042f

// ---------------------------------------------------------------- convert (1 launch)
__global__ __launch_bounds__(256) void cvt_all(
        const float* __restrict__ x,  const float* __restrict__ Wq,
        const float* __restrict__ Wk, const float* __restrict__ Wv,
        const float* __restrict__ Wo,
        __bf16* __restrict__ xb, __bf16* __restrict__ wqkv, __bf16* __restrict__ wob) {
    size_t i = ((size_t)blockIdx.x * 256 + threadIdx.x) * 4;
    const float* src; __bf16* dst; size_t off; float scale = 1.f;
    if (i < XE)               { src = x;  dst = xb;          off = i; }
    else if (i < XE + WE)     { src = Wq; dst = wqkv;        off = i - XE; scale = SCALE_FOLD; }
    else if (i < XE + 2 * WE) { src = Wk; dst = wqkv + WE;   off = i - XE - WE; }
    else if (i < XE + 3 * WE) { src = Wv; dst = wqkv + 2*WE; off = i - XE - 2*WE; }
    else                      { src = Wo; dst = wob;         off = i - XE - 3*WE; }
    float4 v = *(const float4*)(src + off);
    v4bf o;
    o[0] = (__bf16)(v.x * scale); o[1] = (__bf16)(v.y * scale);
    o[2] = (__bf16)(v.z * scale); o[3] = (__bf16)(v.w * scale);
    *(v4bf*)(dst + off) = o;
}

// ---------------------------------------------------------------- fused QKV GEMM, 128x128 tile
__global__ __launch_bounds__(256) void gemm_qkv(
        const __bf16* __restrict__ A, const __bf16* __restrict__ B,
        __bf16* __restrict__ C, __bf16* __restrict__ vt) {
    __shared__ __bf16 As[128][40];
    __shared__ __bf16 Bs[128][40];
    const int t    = threadIdx.x;
    const int lane = t & 63, w = t >> 6;
    const int quad = lane >> 4, l15 = lane & 15;
    const int wm = w & 1, wn = w >> 1;
    const int bm = blockIdx.y * 128, bn = blockIdx.x * 128;
    const int r0 = t >> 2, c0 = (t & 3) * 8;

    v4f acc[4][4] = {};
    for (int k0 = 0; k0 < FEAT; k0 += 32) {
        *(float4*)&As[r0     ][c0] = *(const float4*)(A + (size_t)(bm + r0     ) * FEAT + k0 + c0);
        *(float4*)&As[r0 + 64][c0] = *(const float4*)(A + (size_t)(bm + r0 + 64) * FEAT + k0 + c0);
        *(float4*)&Bs[r0     ][c0] = *(const float4*)(B + (size_t)(bn + r0     ) * FEAT + k0 + c0);
        *(float4*)&Bs[r0 + 64][c0] = *(const float4*)(B + (size_t)(bn + r0 + 64) * FEAT + k0 + c0);
        __syncthreads();
        v8bf a[4], b[4];
#pragma unroll
        for (int mi = 0; mi < 4; mi++) a[mi] = *(const v8bf*)&As[wm * 64 + mi * 16 + l15][quad * 8];
#pragma unroll
        for (int ni = 0; ni < 4; ni++) b[ni] = *(const v8bf*)&Bs[wn * 64 + ni * 16 + l15][quad * 8];
#pragma unroll
        for (int mi = 0; mi < 4; mi++)
#pragma unroll
            for (int ni = 0; ni < 4; ni++)
                acc[mi][ni] = __builtin_amdgcn_mfma_f32_16x16x32_bf16(a[mi], b[ni], acc[mi][ni], 0, 0, 0);
        __syncthreads();
    }
    if (bn < 2 * FEAT) {
#pragma unroll
        for (int mi = 0; mi < 4; mi++)
#pragma unroll
            for (int ni = 0; ni < 4; ni++) {
                int col = bn + wn * 64 + ni * 16 + l15;
#pragma unroll
                for (int r = 0; r < 4; r++) {
                    int row = bm + wm * 64 + mi * 16 + quad * 4 + r;
                    C[(size_t)row * QKV_LD + col] = (__bf16)acc[mi][ni][r];
                }
            }
    } else {                     // V region: transposed packed store vt[col-1536][row]
#pragma unroll
        for (int mi = 0; mi < 4; mi++)
#pragma unroll
            for (int ni = 0; ni < 4; ni++) {
                int col = bn + wn * 64 + ni * 16 + l15 - 2 * FEAT;
                int row = bm + wm * 64 + mi * 16 + quad * 4;
                v4bf pk;
#pragma unroll
                for (int r = 0; r < 4; r++) pk[r] = (__bf16)acc[mi][ni][r];
                *(v4bf*)(vt + (size_t)col * N_TOK + row) = pk;
            }
    }
}

// ---------------------------------------------------------------- attention v3
// 32 q-rows per wave, 128 per block; depth-1 register prefetch of K,V frags;
// barrier-free (P round-trip is intra-wave). Wq pre-scaled by 0.125*log2e.
__global__ __launch_bounds__(256, 2) void attention(
        const __bf16* __restrict__ QKV, const __bf16* __restrict__ vt,
        __bf16* __restrict__ Opart, float* __restrict__ lpart) {
    __shared__ __bf16 P[4][32][68];
    const int t    = threadIdx.x;
    const int lane = t & 63, w = t >> 6;
    const int quad = lane >> 4, l15 = lane & 15;
    const int h = blockIdx.y, s = blockIdx.z;
    const int q0 = blockIdx.x * 128 + w * 32;

    v8bf qf[2][2];
#pragma unroll
    for (int mh = 0; mh < 2; mh++) {
        const __bf16* qp = QKV + (size_t)(q0 + mh * 16 + l15) * QKV_LD + h * DHEAD + quad * 8;
        qf[mh][0] = *(const v8bf*)qp;
        qf[mh][1] = *(const v8bf*)(qp + 32);
    }
    const __bf16* kbase = QKV + FEAT + h * DHEAD + quad * 8 + (size_t)l15 * QKV_LD;
    const __bf16* vbase = vt + (size_t)(h * DHEAD + l15) * N_TOK + quad * 8;

    v4f o_acc[2][4] = {};
    float lacc[2][4] = {{0.f,0.f,0.f,0.f},{0.f,0.f,0.f,0.f}};

    const int kvbeg = s * KV_PER, kvend = kvbeg + KV_PER;

    auto load_kv = [&](int kv, v8bf kf[4][2], v8bf vf[2][4]) {
#pragma unroll
        for (int nt = 0; nt < 4; nt++) {
            const __bf16* kp = kbase + (size_t)(kv + nt * 16) * QKV_LD;
            kf[nt][0] = *(const v8bf*)kp;
            kf[nt][1] = *(const v8bf*)(kp + 32);
        }
#pragma unroll
        for (int ks = 0; ks < 2; ks++)
#pragma unroll
            for (int dt = 0; dt < 4; dt++)
                vf[ks][dt] = *(const v8bf*)(vbase + (size_t)dt * 16 * N_TOK + kv + ks * 32);
    };

    auto step = [&](v8bf kf[4][2], v8bf vf[2][4]) {
        v4f sv[2][4];
#pragma unroll
        for (int mh = 0; mh < 2; mh++)
#pragma unroll
            for (int nt = 0; nt < 4; nt++) {
                v4f a = {};
                a = __builtin_amdgcn_mfma_f32_16x16x32_bf16(qf[mh][0], kf[nt][0], a, 0, 0, 0);
                a = __builtin_amdgcn_mfma_f32_16x16x32_bf16(qf[mh][1], kf[nt][1], a, 0, 0, 0);
                sv[mh][nt] = a;
            }
#pragma unroll
        for (int mh = 0; mh < 2; mh++)
#pragma unroll
            for (int r = 0; r < 4; r++) {
                float p0 = __builtin_amdgcn_exp2f(sv[mh][0][r]);
                float p1 = __builtin_amdgcn_exp2f(sv[mh][1][r]);
                float p2 = __builtin_amdgcn_exp2f(sv[mh][2][r]);
                float p3 = __builtin_amdgcn_exp2f(sv[mh][3][r]);
                lacc[mh][r] += (p0 + p1) + (p2 + p3);
                P[w][mh * 16 + quad * 4 + r][ 0 + l15] = (__bf16)p0;
                P[w][mh * 16 + quad * 4 + r][16 + l15] = (__bf16)p1;
                P[w][mh * 16 + quad * 4 + r][32 + l15] = (__bf16)p2;
                P[w][mh * 16 + quad * 4 + r][48 + l15] = (__bf16)p3;
            }
#pragma unroll
        for (int mh = 0; mh < 2; mh++)
#pragma unroll
            for (int ks = 0; ks < 2; ks++) {
                v8bf pa = *(const v8bf*)&P[w][mh * 16 + l15][ks * 32 + quad * 8];
#pragma unroll
                for (int dt = 0; dt < 4; dt++)
                    o_acc[mh][dt] = __builtin_amdgcn_mfma_f32_16x16x32_bf16(pa, vf[ks][dt], o_acc[mh][dt], 0, 0, 0);
            }
    };

    v8bf kfA[4][2], vfA[2][4], kfB[4][2], vfB[2][4];
    load_kv(kvbeg, kfA, vfA);
    for (int kv0 = kvbeg; kv0 < kvend; kv0 += 128) {
        load_kv(kv0 + 64, kfB, vfB);           // prefetch tile i+1
        step(kfA, vfA);                        // compute tile i
        int kv2 = kv0 + 128;
        load_kv(kv2 < kvend ? kv2 : kvbeg, kfA, vfA);   // prefetch tile i+2 (wrap = harmless)
        step(kfB, vfB);                        // compute tile i+1
    }

    // ---- epilogue: reduce l across 16 col-lanes; store normalized bf16 partial + l
    __bf16* op = Opart + (size_t)s * XE;
#pragma unroll
    for (int mh = 0; mh < 2; mh++)
#pragma unroll
        for (int r = 0; r < 4; r++) {
            float l = lacc[mh][r];
            l += __shfl_xor(l, 1); l += __shfl_xor(l, 2);
            l += __shfl_xor(l, 4); l += __shfl_xor(l, 8);
            float linv = 1.0f / l;
            int row = q0 + mh * 16 + quad * 4 + r;
            if (l15 == 0) lpart[((size_t)s * HEADS + h) * N_TOK + row] = l;
#pragma unroll
            for (int dt = 0; dt < 4; dt++)
                op[(size_t)row * FEAT + h * DHEAD + dt * 16 + l15] = (__bf16)(o_acc[mh][dt][r] * linv);
        }
}

// ---------------------------------------------------------------- combine split partials
__global__ __launch_bounds__(256) void combine(
        const __bf16* __restrict__ Op, const float* __restrict__ lp, __bf16* __restrict__ Ob) {
    size_t i = ((size_t)blockIdx.x * 256 + threadIdx.x) * 4;
    int row = (int)(i / FEAT), col = (int)(i % FEAT), h = col >> 6;
    float ls[SPLIT], tot = 0.f;
#pragma unroll
    for (int s = 0; s < SPLIT; s++) {
        ls[s] = lp[((size_t)s * HEADS + h) * N_TOK + row];
        tot += ls[s];
    }
    float inv = 1.0f / tot;
    float a0 = 0.f, a1 = 0.f, a2 = 0.f, a3 = 0.f;
#pragma unroll
    for (int s = 0; s < SPLIT; s++) {
        v4bf p = *(const v4bf*)(Op + s * XE + i);
        float wgt = ls[s] * inv;
        a0 += wgt * (float)p[0]; a1 += wgt * (float)p[1];
        a2 += wgt * (float)p[2]; a3 += wgt * (float)p[3];
    }
    v4bf o;
    o[0] = (__bf16)a0; o[1] = (__bf16)a1; o[2] = (__bf16)a2; o[3] = (__bf16)a3;
    *(v4bf*)(Ob + i) = o;
}

// ---------------------------------------------------------------- output proj + residual, 128x128 tile
__global__ __launch_bounds__(256) void gemm_out(
        const __bf16* __restrict__ A, const __bf16* __restrict__ B,
        float* __restrict__ Cf, const float* __restrict__ resid) {
    __shared__ __bf16 As[128][40];
    __shared__ __bf16 Bs[128][40];
    const int t    = threadIdx.x;
    const int lane = t & 63, w = t >> 6;
    const int quad = lane >> 4, l15 = lane & 15;
    const int wm = w & 1, wn = w >> 1;
    const int bm = blockIdx.y * 128, bn = blockIdx.x * 128;
    const int r0 = t >> 2, c0 = (t & 3) * 8;

    v4f acc[4][4] = {};
    for (int k0 = 0; k0 < FEAT; k0 += 32) {
        *(float4*)&As[r0     ][c0] = *(const float4*)(A + (size_t)(bm + r0     ) * FEAT + k0 + c0);
        *(float4*)&As[r0 + 64][c0] = *(const float4*)(A + (size_t)(bm + r0 + 64) * FEAT + k0 + c0);
        *(float4*)&Bs[r0     ][c0] = *(const float4*)(B + (size_t)(bn + r0     ) * FEAT + k0 + c0);
        *(float4*)&Bs[r0 + 64][c0] = *(const float4*)(B + (size_t)(bn + r0 + 64) * FEAT + k0 + c0);
        __syncthreads();
        v8bf a[4], b[4];
#pragma unroll
        for (int mi = 0; mi < 4; mi++) a[mi] = *(const v8bf*)&As[wm * 64 + mi * 16 + l15][quad * 8];
#pragma unroll
        for (int ni = 0; ni < 4; ni++) b[ni] = *(const v8bf*)&Bs[wn * 64 + ni * 16 + l15][quad * 8];
#pragma unroll
        for (int mi = 0; mi < 4; mi++)
#pragma unroll
            for (int ni = 0; ni < 4; ni++)
                acc[mi][ni] = __builtin_amdgcn_mfma_f32_16x16x32_bf16(a[mi], b[ni], acc[mi][ni], 0, 0, 0);
        __syncthreads();
    }
#pragma unroll
    for (int mi = 0; mi < 4; mi++)
#pragma unroll
        for (int ni = 0; ni < 4; ni++) {
            int col = bn + wn * 64 + ni * 16 + l15;
#pragma unroll
            for (int r = 0; r < 4; r++) {
                int row = bm + wm * 64 + mi * 16 + quad * 4 + r;
                Cf[(size_t)row * FEAT + col] = acc[mi][ni][r] + resid[(size_t)row * FEAT + col];
            }
        }
}

// ---------------------------------------------------------------- layernorm
__global__ __launch_bounds__(256) void ln_kernel(
        const float* __restrict__ Y, const float* __restrict__ gamma,
        const float* __restrict__ beta, float* __restrict__ out) {
    __shared__ float sbuf[4];
    const int row = blockIdx.x, t = threadIdx.x;
    const float* y = Y + (size_t)row * FEAT;
    float v0 = y[t], v1 = y[t + 256], v2 = y[t + 512];
    float s = v0 + v1 + v2;
#pragma unroll
    for (int m = 32; m; m >>= 1) s += __shfl_xor(s, m);
    if ((t & 63) == 0) sbuf[t >> 6] = s;
    __syncthreads();
    float mean = (sbuf[0] + sbuf[1] + sbuf[2] + sbuf[3]) * (1.f / FEAT);
    __syncthreads();
    float d0 = v0 - mean, d1 = v1 - mean, d2 = v2 - mean;
    float q = d0 * d0 + d1 * d1 + d2 * d2;
#pragma unroll
    for (int m = 32; m; m >>= 1) q += __shfl_xor(q, m);
    if ((t & 63) == 0) sbuf[t >> 6] = q;
    __syncthreads();
    float var = (sbuf[0] + sbuf[1] + sbuf[2] + sbuf[3]) * (1.f / FEAT);
    float rs = rsqrtf(var + 1e-12f);
    float* o = out + (size_t)row * FEAT;
    o[t]       = d0 * rs * gamma[t]       + beta[t];
    o[t + 256] = d1 * rs * gamma[t + 256] + beta[t + 256];
    o[t + 512] = d2 * rs * gamma[t + 512] + beta[t + 512];
}

// ---------------------------------------------------------------- launch
extern "C" void kernel_launch(void* const* d_in, const int* in_sizes, int n_in,
                              void* d_out, int out_size, void* d_ws, size_t ws_size,
                              hipStream_t stream) {
    const float* x     = (const float*)d_in[0];
    const float* Wq    = (const float*)d_in[1];
    const float* Wk    = (const float*)d_in[2];
    const float* Wv    = (const float*)d_in[3];
    const float* Wo    = (const float*)d_in[4];
    const float* gamma = (const float*)d_in[5];
    const float* beta  = (const float*)d_in[6];
    float* out = (float*)d_out;

    char* ws = (char*)d_ws;
    size_t off = 0;
    auto alloc = [&](size_t bytes) -> void* {
        void* p = ws + off;
        off += (bytes + 255) & ~(size_t)255;
        return p;
    };
    __bf16* xb   = (__bf16*)alloc(XE * 2);            // dead after gemm_qkv
    __bf16* wqkv = (__bf16*)alloc(3 * WE * 2);        // dead after gemm_qkv
    __bf16* wob  = (__bf16*)alloc(WE * 2);
    __bf16* qkv  = (__bf16*)alloc(XE * 3 * 2);        // [Q'|K|(unused V)] stride 2304
    __bf16* vtb  = (__bf16*)alloc((size_t)FEAT * N_TOK * 2);   // V^T [768][2048]
    __bf16* Ob   = (__bf16*)alloc(XE * 2);
    __bf16* Op   = (__bf16*)alloc(SPLIT * XE * 2);    // normalized split partials
    float*  lp   = (float*)alloc(SPLIT * HEADS * N_TOK * 4);
    float*  Yf   = (float*)ws;                        // aliases xb+wqkv (dead by gemm_out)

    cvt_all<<<(int)((XE + 4 * WE) / 4 / 256), 256, 0, stream>>>(x, Wq, Wk, Wv, Wo, xb, wqkv, wob);

    gemm_qkv<<<dim3(QKV_LD / 128, N_TOK / 128), 256, 0, stream>>>(xb, wqkv, qkv, vtb);

    attention<<<dim3(N_TOK / 128, HEADS, SPLIT), 256, 0, stream>>>(qkv, vtb, Op, lp);

    combine<<<(int)(XE / 4 / 256), 256, 0, stream>>>(Op, lp, Ob);

    gemm_out<<<dim3(FEAT / 128, N_TOK / 128), 256, 0, stream>>>(Ob, wob, Yf, x);

    ln_kernel<<<N_TOK, 256, 0, stream>>>(Yf, gamma, beta, out);
}

// Round 5
// 179.960 us; speedup vs baseline: 1.2138x; 1.0222x over previous
//
#include <hip/hip_runtime.h>
#include <hip/hip_bf16.h>
#include <math.h>

#define N_TOK 2048
#define FEAT  768
#define HEADS 12
#define DHEAD 64
#define SPLIT 8
#define KV_PER (N_TOK / SPLIT)

typedef __bf16 v8bf __attribute__((ext_vector_type(8)));
typedef __bf16 v4bf __attribute__((ext_vector_type(4)));
typedef float  v4f  __attribute__((ext_vector_type(4)));

#define XE ((size_t)N_TOK * FEAT)   // 1572864
#define WE ((size_t)FEAT * FEAT)    //  589824
#define QK_LD 1536                  // [Q'|K] row stride

// fold (1/sqrt(64)) * log2(e) into Wq so softmax is a bare exp2
#define SCALE_FOLD 0.18033688011112042f

// async global->LDS, 16B per lane; lds dest must be wave-uniform base + lane*16
__device__ __forceinline__ void gload16(const __bf16* g, __bf16* l) {
    __builtin_amdgcn_global_load_lds(
        (const __attribute__((address_space(1))) unsigned int*)g,
        (__attribute__((address_space(3))) unsigned int*)l, 16, 0, 0);
}

// ---------------------------------------------------------------- convert (1 launch)
__global__ __launch_bounds__(256) void cvt_all(
        const float* __restrict__ x,  const float* __restrict__ Wq,
        const float* __restrict__ Wk, const float* __restrict__ Wv,
        const float* __restrict__ Wo,
        __bf16* __restrict__ xb, __bf16* __restrict__ wqkv, __bf16* __restrict__ wob) {
    size_t i = ((size_t)blockIdx.x * 256 + threadIdx.x) * 4;
    const float* src; __bf16* dst; size_t off; float scale = 1.f;
    if (i < XE)               { src = x;  dst = xb;          off = i; }
    else if (i < XE + WE)     { src = Wq; dst = wqkv;        off = i - XE; scale = SCALE_FOLD; }
    else if (i < XE + 2 * WE) { src = Wk; dst = wqkv + WE;   off = i - XE - WE; }
    else if (i < XE + 3 * WE) { src = Wv; dst = wqkv + 2*WE; off = i - XE - 2*WE; }
    else                      { src = Wo; dst = wob;         off = i - XE - 3*WE; }
    float4 v = *(const float4*)(src + off);
    v4bf o;
    o[0] = (__bf16)(v.x * scale); o[1] = (__bf16)(v.y * scale);
    o[2] = (__bf16)(v.z * scale); o[3] = (__bf16)(v.w * scale);
    *(v4bf*)(dst + off) = o;
}

// ---------------------------------------------------------------- fused QKV GEMM
// 64x128 tile, BK=32, global_load_lds staging. C = x . [Wq'|Wk|Wv]^T.
// QK cols (bn<1536) -> qk row-major stride 1536; V cols -> vt transposed [768][2048].
__global__ __launch_bounds__(256) void gemm_qkv(
        const __bf16* __restrict__ A, const __bf16* __restrict__ B,
        __bf16* __restrict__ qk, __bf16* __restrict__ vt) {
    __shared__ __bf16 As[64][32];
    __shared__ __bf16 Bs[128][32];
    const int t    = threadIdx.x;
    const int lane = t & 63, w = t >> 6;
    const int quad = lane >> 4, l15 = lane & 15;
    const int wm = w & 1, wn = w >> 1;
    const int bm = blockIdx.y * 64, bn = blockIdx.x * 128;
    const int srow = lane >> 2, scol = (lane & 3) * 8;   // lane->16B slot

    v4f acc[2][4] = {};
    for (int k0 = 0; k0 < FEAT; k0 += 32) {
        gload16(A + (size_t)(bm +       w * 16 + srow) * FEAT + k0 + scol, &As[w * 16][0]);
        gload16(B + (size_t)(bn +       w * 16 + srow) * FEAT + k0 + scol, &Bs[w * 16][0]);
        gload16(B + (size_t)(bn + 64 +  w * 16 + srow) * FEAT + k0 + scol, &Bs[64 + w * 16][0]);
        __syncthreads();
        v8bf a[2], b[4];
#pragma unroll
        for (int mi = 0; mi < 2; mi++) a[mi] = *(const v8bf*)&As[wm * 32 + mi * 16 + l15][quad * 8];
#pragma unroll
        for (int ni = 0; ni < 4; ni++) b[ni] = *(const v8bf*)&Bs[wn * 64 + ni * 16 + l15][quad * 8];
#pragma unroll
        for (int mi = 0; mi < 2; mi++)
#pragma unroll
            for (int ni = 0; ni < 4; ni++)
                acc[mi][ni] = __builtin_amdgcn_mfma_f32_16x16x32_bf16(a[mi], b[ni], acc[mi][ni], 0, 0, 0);
        __syncthreads();
    }
    if (bn < QK_LD) {            // Q,K region
#pragma unroll
        for (int mi = 0; mi < 2; mi++)
#pragma unroll
            for (int ni = 0; ni < 4; ni++) {
                int col = bn + wn * 64 + ni * 16 + l15;
#pragma unroll
                for (int r = 0; r < 4; r++) {
                    int row = bm + wm * 32 + mi * 16 + quad * 4 + r;
                    qk[(size_t)row * QK_LD + col] = (__bf16)acc[mi][ni][r];
                }
            }
    } else {                     // V region: transposed packed store vt[col-1536][row]
#pragma unroll
        for (int mi = 0; mi < 2; mi++)
#pragma unroll
            for (int ni = 0; ni < 4; ni++) {
                int col = bn + wn * 64 + ni * 16 + l15 - QK_LD;
                int row = bm + wm * 32 + mi * 16 + quad * 4;
                v4bf pk;
#pragma unroll
                for (int r = 0; r < 4; r++) pk[r] = (__bf16)acc[mi][ni][r];
                *(v4bf*)(vt + (size_t)col * N_TOK + row) = pk;
            }
    }
}

// ---------------------------------------------------------------- attention
// 32 q-rows per wave, 128 per block; depth-1 register prefetch; barrier-free.
__global__ __launch_bounds__(256, 2) void attention(
        const __bf16* __restrict__ QK, const __bf16* __restrict__ vt,
        __bf16* __restrict__ Opart, float* __restrict__ lpart) {
    __shared__ __bf16 P[4][32][68];
    const int t    = threadIdx.x;
    const int lane = t & 63, w = t >> 6;
    const int quad = lane >> 4, l15 = lane & 15;
    const int h = blockIdx.y, s = blockIdx.z;
    const int q0 = blockIdx.x * 128 + w * 32;

    v8bf qf[2][2];
#pragma unroll
    for (int mh = 0; mh < 2; mh++) {
        const __bf16* qp = QK + (size_t)(q0 + mh * 16 + l15) * QK_LD + h * DHEAD + quad * 8;
        qf[mh][0] = *(const v8bf*)qp;
        qf[mh][1] = *(const v8bf*)(qp + 32);
    }
    const __bf16* kbase = QK + FEAT + h * DHEAD + quad * 8 + (size_t)l15 * QK_LD;
    const __bf16* vbase = vt + (size_t)(h * DHEAD + l15) * N_TOK + quad * 8;

    v4f o_acc[2][4] = {};
    float lacc[2][4] = {{0.f,0.f,0.f,0.f},{0.f,0.f,0.f,0.f}};

    const int kvbeg = s * KV_PER, kvend = kvbeg + KV_PER;

    auto load_kv = [&](int kv, v8bf kf[4][2], v8bf vf[2][4]) {
#pragma unroll
        for (int nt = 0; nt < 4; nt++) {
            const __bf16* kp = kbase + (size_t)(kv + nt * 16) * QK_LD;
            kf[nt][0] = *(const v8bf*)kp;
            kf[nt][1] = *(const v8bf*)(kp + 32);
        }
#pragma unroll
        for (int ks = 0; ks < 2; ks++)
#pragma unroll
            for (int dt = 0; dt < 4; dt++)
                vf[ks][dt] = *(const v8bf*)(vbase + (size_t)dt * 16 * N_TOK + kv + ks * 32);
    };

    auto step = [&](v8bf kf[4][2], v8bf vf[2][4]) {
        v4f sv[2][4];
#pragma unroll
        for (int mh = 0; mh < 2; mh++)
#pragma unroll
            for (int nt = 0; nt < 4; nt++) {
                v4f a = {};
                a = __builtin_amdgcn_mfma_f32_16x16x32_bf16(qf[mh][0], kf[nt][0], a, 0, 0, 0);
                a = __builtin_amdgcn_mfma_f32_16x16x32_bf16(qf[mh][1], kf[nt][1], a, 0, 0, 0);
                sv[mh][nt] = a;
            }
#pragma unroll
        for (int mh = 0; mh < 2; mh++)
#pragma unroll
            for (int r = 0; r < 4; r++) {
                float p0 = __builtin_amdgcn_exp2f(sv[mh][0][r]);
                float p1 = __builtin_amdgcn_exp2f(sv[mh][1][r]);
                float p2 = __builtin_amdgcn_exp2f(sv[mh][2][r]);
                float p3 = __builtin_amdgcn_exp2f(sv[mh][3][r]);
                lacc[mh][r] += (p0 + p1) + (p2 + p3);
                P[w][mh * 16 + quad * 4 + r][ 0 + l15] = (__bf16)p0;
                P[w][mh * 16 + quad * 4 + r][16 + l15] = (__bf16)p1;
                P[w][mh * 16 + quad * 4 + r][32 + l15] = (__bf16)p2;
                P[w][mh * 16 + quad * 4 + r][48 + l15] = (__bf16)p3;
            }
#pragma unroll
        for (int mh = 0; mh < 2; mh++)
#pragma unroll
            for (int ks = 0; ks < 2; ks++) {
                v8bf pa = *(const v8bf*)&P[w][mh * 16 + l15][ks * 32 + quad * 8];
#pragma unroll
                for (int dt = 0; dt < 4; dt++)
                    o_acc[mh][dt] = __builtin_amdgcn_mfma_f32_16x16x32_bf16(pa, vf[ks][dt], o_acc[mh][dt], 0, 0, 0);
            }
    };

    v8bf kfA[4][2], vfA[2][4], kfB[4][2], vfB[2][4];
    load_kv(kvbeg, kfA, vfA);
    for (int kv0 = kvbeg; kv0 < kvend; kv0 += 128) {
        load_kv(kv0 + 64, kfB, vfB);           // prefetch tile i+1
        step(kfA, vfA);                        // compute tile i
        int kv2 = kv0 + 128;
        load_kv(kv2 < kvend ? kv2 : kvbeg, kfA, vfA);   // prefetch tile i+2 (wrap = harmless)
        step(kfB, vfB);                        // compute tile i+1
    }

    __bf16* op = Opart + (size_t)s * XE;
#pragma unroll
    for (int mh = 0; mh < 2; mh++)
#pragma unroll
        for (int r = 0; r < 4; r++) {
            float l = lacc[mh][r];
            l += __shfl_xor(l, 1); l += __shfl_xor(l, 2);
            l += __shfl_xor(l, 4); l += __shfl_xor(l, 8);
            float linv = 1.0f / l;
            int row = q0 + mh * 16 + quad * 4 + r;
            if (l15 == 0) lpart[((size_t)s * HEADS + h) * N_TOK + row] = l;
#pragma unroll
            for (int dt = 0; dt < 4; dt++)
                op[(size_t)row * FEAT + h * DHEAD + dt * 16 + l15] = (__bf16)(o_acc[mh][dt][r] * linv);
        }
}

// ---------------------------------------------------------------- combine split partials
__global__ __launch_bounds__(256) void combine(
        const __bf16* __restrict__ Op, const float* __restrict__ lp, __bf16* __restrict__ Ob) {
    size_t i = ((size_t)blockIdx.x * 256 + threadIdx.x) * 4;
    int row = (int)(i / FEAT), col = (int)(i % FEAT), h = col >> 6;
    float ls[SPLIT], tot = 0.f;
#pragma unroll
    for (int s = 0; s < SPLIT; s++) {
        ls[s] = lp[((size_t)s * HEADS + h) * N_TOK + row];
        tot += ls[s];
    }
    float inv = 1.0f / tot;
    float a0 = 0.f, a1 = 0.f, a2 = 0.f, a3 = 0.f;
#pragma unroll
    for (int s = 0; s < SPLIT; s++) {
        v4bf p = *(const v4bf*)(Op + s * XE + i);
        float wgt = ls[s] * inv;
        a0 += wgt * (float)p[0]; a1 += wgt * (float)p[1];
        a2 += wgt * (float)p[2]; a3 += wgt * (float)p[3];
    }
    v4bf o;
    o[0] = (__bf16)a0; o[1] = (__bf16)a1; o[2] = (__bf16)a2; o[3] = (__bf16)a3;
    *(v4bf*)(Ob + i) = o;
}

// ---------------------------------------------------------------- output proj + residual
// 64x128 tile, BK=32, global_load_lds staging.
__global__ __launch_bounds__(256) void gemm_out(
        const __bf16* __restrict__ A, const __bf16* __restrict__ B,
        float* __restrict__ Cf, const float* __restrict__ resid) {
    __shared__ __bf16 As[64][32];
    __shared__ __bf16 Bs[128][32];
    const int t    = threadIdx.x;
    const int lane = t & 63, w = t >> 6;
    const int quad = lane >> 4, l15 = lane & 15;
    const int wm = w & 1, wn = w >> 1;
    const int bm = blockIdx.y * 64, bn = blockIdx.x * 128;
    const int srow = lane >> 2, scol = (lane & 3) * 8;

    v4f acc[2][4] = {};
    for (int k0 = 0; k0 < FEAT; k0 += 32) {
        gload16(A + (size_t)(bm +      w * 16 + srow) * FEAT + k0 + scol, &As[w * 16][0]);
        gload16(B + (size_t)(bn +      w * 16 + srow) * FEAT + k0 + scol, &Bs[w * 16][0]);
        gload16(B + (size_t)(bn + 64 + w * 16 + srow) * FEAT + k0 + scol, &Bs[64 + w * 16][0]);
        __syncthreads();
        v8bf a[2], b[4];
#pragma unroll
        for (int mi = 0; mi < 2; mi++) a[mi] = *(const v8bf*)&As[wm * 32 + mi * 16 + l15][quad * 8];
#pragma unroll
        for (int ni = 0; ni < 4; ni++) b[ni] = *(const v8bf*)&Bs[wn * 64 + ni * 16 + l15][quad * 8];
#pragma unroll
        for (int mi = 0; mi < 2; mi++)
#pragma unroll
            for (int ni = 0; ni < 4; ni++)
                acc[mi][ni] = __builtin_amdgcn_mfma_f32_16x16x32_bf16(a[mi], b[ni], acc[mi][ni], 0, 0, 0);
        __syncthreads();
    }
#pragma unroll
    for (int mi = 0; mi < 2; mi++)
#pragma unroll
        for (int ni = 0; ni < 4; ni++) {
            int col = bn + wn * 64 + ni * 16 + l15;
#pragma unroll
            for (int r = 0; r < 4; r++) {
                int row = bm + wm * 32 + mi * 16 + quad * 4 + r;
                Cf[(size_t)row * FEAT + col] = acc[mi][ni][r] + resid[(size_t)row * FEAT + col];
            }
        }
}

// ---------------------------------------------------------------- layernorm
__global__ __launch_bounds__(256) void ln_kernel(
        const float* __restrict__ Y, const float* __restrict__ gamma,
        const float* __restrict__ beta, float* __restrict__ out) {
    __shared__ float sbuf[4];
    const int row = blockIdx.x, t = threadIdx.x;
    const float* y = Y + (size_t)row * FEAT;
    float v0 = y[t], v1 = y[t + 256], v2 = y[t + 512];
    float s = v0 + v1 + v2;
#pragma unroll
    for (int m = 32; m; m >>= 1) s += __shfl_xor(s, m);
    if ((t & 63) == 0) sbuf[t >> 6] = s;
    __syncthreads();
    float mean = (sbuf[0] + sbuf[1] + sbuf[2] + sbuf[3]) * (1.f / FEAT);
    __syncthreads();
    float d0 = v0 - mean, d1 = v1 - mean, d2 = v2 - mean;
    float q = d0 * d0 + d1 * d1 + d2 * d2;
#pragma unroll
    for (int m = 32; m; m >>= 1) q += __shfl_xor(q, m);
    if ((t & 63) == 0) sbuf[t >> 6] = q;
    __syncthreads();
    float var = (sbuf[0] + sbuf[1] + sbuf[2] + sbuf[3]) * (1.f / FEAT);
    float rs = rsqrtf(var + 1e-12f);
    float* o = out + (size_t)row * FEAT;
    o[t]       = d0 * rs * gamma[t]       + beta[t];
    o[t + 256] = d1 * rs * gamma[t + 256] + beta[t + 256];
    o[t + 512] = d2 * rs * gamma[t + 512] + beta[t + 512];
}

// ---------------------------------------------------------------- launch
extern "C" void kernel_launch(void* const* d_in, const int* in_sizes, int n_in,
                              void* d_out, int out_size, void* d_ws, size_t ws_size,
                              hipStream_t stream) {
    const float* x     = (const float*)d_in[0];
    const float* Wq    = (const float*)d_in[1];
    const float* Wk    = (const float*)d_in[2];
    const float* Wv    = (const float*)d_in[3];
    const float* Wo    = (const float*)d_in[4];
    const float* gamma = (const float*)d_in[5];
    const float* beta  = (const float*)d_in[6];
    float* out = (float*)d_out;

    char* ws = (char*)d_ws;
    size_t off = 0;
    auto alloc = [&](size_t bytes) -> void* {
        void* p = ws + off;
        off += (bytes + 255) & ~(size_t)255;
        return p;
    };
    __bf16* xb   = (__bf16*)alloc(XE * 2);            // dead after gemm_qkv
    __bf16* wqkv = (__bf16*)alloc(3 * WE * 2);        // dead after gemm_qkv
    __bf16* wob  = (__bf16*)alloc(WE * 2);
    __bf16* qk   = (__bf16*)alloc((size_t)N_TOK * QK_LD * 2);  // [Q'|K] stride 1536
    __bf16* vtb  = (__bf16*)alloc((size_t)FEAT * N_TOK * 2);   // V^T [768][2048]; dead after attention
    __bf16* Op   = (__bf16*)alloc(SPLIT * XE * 2);    // normalized split partials
    float*  lp   = (float*)alloc(SPLIT * HEADS * N_TOK * 4);
    __bf16* Ob   = vtb;                               // aliases vt (dead by combine)
    float*  Yf   = (float*)ws;                        // aliases xb+wqkv (dead by gemm_out)

    cvt_all<<<(int)((XE + 4 * WE) / 4 / 256), 256, 0, stream>>>(x, Wq, Wk, Wv, Wo, xb, wqkv, wob);

    gemm_qkv<<<dim3((QK_LD + FEAT) / 128, N_TOK / 64), 256, 0, stream>>>(xb, wqkv, qk, vtb);

    attention<<<dim3(N_TOK / 128, HEADS, SPLIT), 256, 0, stream>>>(qk, vtb, Op, lp);

    combine<<<(int)(XE / 4 / 256), 256, 0, stream>>>(Op, lp, Ob);

    gemm_out<<<dim3(FEAT / 128, N_TOK / 64), 256, 0, stream>>>(Ob, wob, Yf, x);

    ln_kernel<<<N_TOK, 256, 0, stream>>>(Yf, gamma, beta, out);
}

// Round 7
// 158.241 us; speedup vs baseline: 1.3804x; 1.1373x over previous
//
#include <hip/hip_runtime.h>
#include <hip/hip_bf16.h>
#include <math.h>

#define N_TOK 2048
#define FEAT  768
#define HEADS 12
#define DHEAD 64
#define SPLIT 4
#define KV_PER (N_TOK / SPLIT)

typedef __bf16 v8bf __attribute__((ext_vector_type(8)));
typedef __bf16 v4bf __attribute__((ext_vector_type(4)));
typedef float  v4f  __attribute__((ext_vector_type(4)));

#define XE ((size_t)N_TOK * FEAT)   // 1572864
#define QK_LD 1536                  // [Q'|K] row stride

// fold (1/sqrt(64)) * log2(e) into Wq so softmax is a bare exp2
#define SCALE_FOLD 0.18033688011112042f

// async global->LDS, 16B/lane; LDS dest = wave-uniform base + lane*16 (m104)
__device__ __forceinline__ void gload16(const __bf16* g, __bf16* l) {
    __builtin_amdgcn_global_load_lds(
        (const __attribute__((address_space(1))) unsigned int*)g,
        (__attribute__((address_space(3))) unsigned int*)l, 16, 0, 0);
}

// ---------------------------------------------------------------- fused QKV GEMM (f32 in, cvt fused)
// C = x . [Wq'|Wk|Wv]^T. 64x128 tile, BK=32. Grid.x = 2304/128 = 18.
// QK cols (bn<1536) -> qk row-major stride 1536; V cols -> vt transposed [768][2048].
__global__ __launch_bounds__(256) void gemm_qkv(
        const float* __restrict__ x,  const float* __restrict__ Wq,
        const float* __restrict__ Wk, const float* __restrict__ Wv,
        __bf16* __restrict__ qk, __bf16* __restrict__ vt) {
    __shared__ __bf16 As[64][32];
    __shared__ __bf16 Bs[128][32];
    const int t    = threadIdx.x;
    const int lane = t & 63, w = t >> 6;
    const int quad = lane >> 4, l15 = lane & 15;
    const int wm = w & 1, wn = w >> 1;
    const int bm = blockIdx.y * 64, bn = blockIdx.x * 128;

    const float* Bsrc; float scale = 1.f; int bc0 = bn;      // block-uniform
    if (bn < FEAT)            { Bsrc = Wq; scale = SCALE_FOLD; }
    else if (bn < 2 * FEAT)   { Bsrc = Wk; bc0 = bn - FEAT; }
    else                      { Bsrc = Wv; bc0 = bn - 2 * FEAT; }

    const int ar = t >> 2, ac = (t & 3) * 8;    // A stager: 64 rows x 32 cols
    const int br = t >> 1, bc = (t & 1) * 16;   // B stager: 128 rows x 32 cols

    v4f acc[2][4] = {};
    for (int k0 = 0; k0 < FEAT; k0 += 32) {
        {   // A: x f32 -> bf16
            const float* ap = x + (size_t)(bm + ar) * FEAT + k0 + ac;
            float4 a0 = *(const float4*)ap, a1 = *(const float4*)(ap + 4);
            v8bf av;
            av[0]=(__bf16)a0.x; av[1]=(__bf16)a0.y; av[2]=(__bf16)a0.z; av[3]=(__bf16)a0.w;
            av[4]=(__bf16)a1.x; av[5]=(__bf16)a1.y; av[6]=(__bf16)a1.z; av[7]=(__bf16)a1.w;
            *(v8bf*)&As[ar][ac] = av;
        }
        {   // B: W f32 -> bf16 (scale folds 0.125*log2e into Wq)
            const float* bp = Bsrc + (size_t)(bc0 + br) * FEAT + k0 + bc;
            float4 b0 = *(const float4*)bp,     b1 = *(const float4*)(bp + 4);
            float4 b2 = *(const float4*)(bp+8), b3 = *(const float4*)(bp + 12);
            v8bf v0, v1;
            v0[0]=(__bf16)(b0.x*scale); v0[1]=(__bf16)(b0.y*scale); v0[2]=(__bf16)(b0.z*scale); v0[3]=(__bf16)(b0.w*scale);
            v0[4]=(__bf16)(b1.x*scale); v0[5]=(__bf16)(b1.y*scale); v0[6]=(__bf16)(b1.z*scale); v0[7]=(__bf16)(b1.w*scale);
            v1[0]=(__bf16)(b2.x*scale); v1[1]=(__bf16)(b2.y*scale); v1[2]=(__bf16)(b2.z*scale); v1[3]=(__bf16)(b2.w*scale);
            v1[4]=(__bf16)(b3.x*scale); v1[5]=(__bf16)(b3.y*scale); v1[6]=(__bf16)(b3.z*scale); v1[7]=(__bf16)(b3.w*scale);
            *(v8bf*)&Bs[br][bc]     = v0;
            *(v8bf*)&Bs[br][bc + 8] = v1;
        }
        __syncthreads();
        v8bf a[2], b[4];
#pragma unroll
        for (int mi = 0; mi < 2; mi++) a[mi] = *(const v8bf*)&As[wm * 32 + mi * 16 + l15][quad * 8];
#pragma unroll
        for (int ni = 0; ni < 4; ni++) b[ni] = *(const v8bf*)&Bs[wn * 64 + ni * 16 + l15][quad * 8];
#pragma unroll
        for (int mi = 0; mi < 2; mi++)
#pragma unroll
            for (int ni = 0; ni < 4; ni++)
                acc[mi][ni] = __builtin_amdgcn_mfma_f32_16x16x32_bf16(a[mi], b[ni], acc[mi][ni], 0, 0, 0);
        __syncthreads();
    }
    if (bn < 2 * FEAT) {         // Q,K region
#pragma unroll
        for (int mi = 0; mi < 2; mi++)
#pragma unroll
            for (int ni = 0; ni < 4; ni++) {
                int col = bn + wn * 64 + ni * 16 + l15;
#pragma unroll
                for (int r = 0; r < 4; r++) {
                    int row = bm + wm * 32 + mi * 16 + quad * 4 + r;
                    qk[(size_t)row * QK_LD + col] = (__bf16)acc[mi][ni][r];
                }
            }
    } else {                     // V region: transposed packed store vt[col-1536][row]
#pragma unroll
        for (int mi = 0; mi < 2; mi++)
#pragma unroll
            for (int ni = 0; ni < 4; ni++) {
                int col = bn + wn * 64 + ni * 16 + l15 - 2 * FEAT;
                int row = bm + wm * 32 + mi * 16 + quad * 4;
                v4bf pk;
#pragma unroll
                for (int r = 0; r < 4; r++) pk[r] = (__bf16)acc[mi][ni][r];
                *(v4bf*)(vt + (size_t)col * N_TOK + row) = pk;
            }
    }
}

// ---------------------------------------------------------------- attention v4
// K,V tiles staged via global_load_lds, shared across the block's 4 waves,
// double-buffered; XOR swizzle on global slot so frag ds_read_b128 is conflict-free.
// 32 q-rows/wave, 128/block. Grid (16, 12, SPLIT).
__global__ __launch_bounds__(256, 3) void attention(
        const __bf16* __restrict__ QK, const __bf16* __restrict__ vt,
        __bf16* __restrict__ Opart, float* __restrict__ lpart) {
    __shared__ __bf16 KV[2][2][64][64];   // [buf][K/V][row][64]; rows 128B, lane-contiguous
    __shared__ __bf16 P[4][32][68];
    const int t    = threadIdx.x;
    const int lane = t & 63, w = t >> 6;
    const int quad = lane >> 4, l15 = lane & 15;
    const int h = blockIdx.y, s = blockIdx.z;
    const int q0 = blockIdx.x * 128 + w * 32;

    v8bf qf[2][2];
#pragma unroll
    for (int mh = 0; mh < 2; mh++) {
        const __bf16* qp = QK + (size_t)(q0 + mh * 16 + l15) * QK_LD + h * DHEAD + quad * 8;
        qf[mh][0] = *(const v8bf*)qp;
        qf[mh][1] = *(const v8bf*)(qp + 32);
    }
    const __bf16* kg = QK + FEAT + h * DHEAD;              // + (kv0+row)*QK_LD + slot*8
    const __bf16* vg = vt + (size_t)(h * DHEAD) * N_TOK;   // + row*N_TOK + kv0 + slot*8

    v4f o_acc[2][4] = {};
    float lacc[2][4] = {{0.f,0.f,0.f,0.f},{0.f,0.f,0.f,0.f}};

    const int kvbeg = s * KV_PER;
    const int lr8 = lane >> 3;          // staging sub-row 0..7

    auto stage = [&](int b, int kv0) {
#pragma unroll
        for (int i = 0; i < 2; i++) {
            int row = w * 16 + i * 8 + lr8;
            int gs  = (lane & 7) ^ (row & 7);              // global-side swizzle
            gload16(kg + (size_t)(kv0 + row) * QK_LD + gs * 8, &KV[b][0][w * 16 + i * 8][0]);
            gload16(vg + (size_t)row * N_TOK + kv0 + gs * 8,   &KV[b][1][w * 16 + i * 8][0]);
        }
    };

    auto step = [&](int b) {
        // ---- K frags from LDS (physical slot = logical ^ (row&7))
        v8bf kf[4][2];
#pragma unroll
        for (int nt = 0; nt < 4; nt++)
#pragma unroll
            for (int ks = 0; ks < 2; ks++)
                kf[nt][ks] = *(const v8bf*)&KV[b][0][nt * 16 + l15][((ks * 4 + quad) ^ (l15 & 7)) * 8];
        v4f sv[2][4];
#pragma unroll
        for (int mh = 0; mh < 2; mh++)
#pragma unroll
            for (int nt = 0; nt < 4; nt++) {
                v4f a = {};
                a = __builtin_amdgcn_mfma_f32_16x16x32_bf16(qf[mh][0], kf[nt][0], a, 0, 0, 0);
                a = __builtin_amdgcn_mfma_f32_16x16x32_bf16(qf[mh][1], kf[nt][1], a, 0, 0, 0);
                sv[mh][nt] = a;
            }
        // ---- p = 2^s, per-lane row-sums, P to per-wave LDS
#pragma unroll
        for (int mh = 0; mh < 2; mh++)
#pragma unroll
            for (int r = 0; r < 4; r++) {
                float p0 = __builtin_amdgcn_exp2f(sv[mh][0][r]);
                float p1 = __builtin_amdgcn_exp2f(sv[mh][1][r]);
                float p2 = __builtin_amdgcn_exp2f(sv[mh][2][r]);
                float p3 = __builtin_amdgcn_exp2f(sv[mh][3][r]);
                lacc[mh][r] += (p0 + p1) + (p2 + p3);
                P[w][mh * 16 + quad * 4 + r][ 0 + l15] = (__bf16)p0;
                P[w][mh * 16 + quad * 4 + r][16 + l15] = (__bf16)p1;
                P[w][mh * 16 + quad * 4 + r][32 + l15] = (__bf16)p2;
                P[w][mh * 16 + quad * 4 + r][48 + l15] = (__bf16)p3;
            }
        // ---- V frags + PV
        v8bf vf[2][4];
#pragma unroll
        for (int ks = 0; ks < 2; ks++)
#pragma unroll
            for (int dt = 0; dt < 4; dt++)
                vf[ks][dt] = *(const v8bf*)&KV[b][1][dt * 16 + l15][((ks * 4 + quad) ^ (l15 & 7)) * 8];
#pragma unroll
        for (int mh = 0; mh < 2; mh++)
#pragma unroll
            for (int ks = 0; ks < 2; ks++) {
                v8bf pa = *(const v8bf*)&P[w][mh * 16 + l15][ks * 32 + quad * 8];
#pragma unroll
                for (int dt = 0; dt < 4; dt++)
                    o_acc[mh][dt] = __builtin_amdgcn_mfma_f32_16x16x32_bf16(pa, vf[ks][dt], o_acc[mh][dt], 0, 0, 0);
            }
    };

    stage(0, kvbeg);
    const int TILES = KV_PER / 64;     // 8
    for (int tt = 0; tt < TILES; tt++) {
        __syncthreads();               // buf[tt&1] staged (vmcnt drain at barrier)
        if (tt + 1 < TILES) stage((tt + 1) & 1, kvbeg + (tt + 1) * 64);
        step(tt & 1);
    }

    // ---- epilogue: reduce l across 16 col-lanes; store normalized bf16 partial + l
    __bf16* op = Opart + (size_t)s * XE;
#pragma unroll
    for (int mh = 0; mh < 2; mh++)
#pragma unroll
        for (int r = 0; r < 4; r++) {
            float l = lacc[mh][r];
            l += __shfl_xor(l, 1); l += __shfl_xor(l, 2);
            l += __shfl_xor(l, 4); l += __shfl_xor(l, 8);
            float linv = 1.0f / l;
            int row = q0 + mh * 16 + quad * 4 + r;
            if (l15 == 0) lpart[((size_t)s * HEADS + h) * N_TOK + row] = l;
#pragma unroll
            for (int dt = 0; dt < 4; dt++)
                op[(size_t)row * FEAT + h * DHEAD + dt * 16 + l15] = (__bf16)(o_acc[mh][dt][r] * linv);
        }
}

// ---------------------------------------------------------------- output proj (combine fused) + residual
// A-tile = weighted sum of SPLIT normalized partials (combine done in stager).
// B = Wo f32 (cvt fused). 64x128 tile, BK=32. Yf = A.Wo^T + x (f32).
__global__ __launch_bounds__(256) void gemm_out(
        const __bf16* __restrict__ Op, const float* __restrict__ lp,
        const float* __restrict__ Wo,  const float* __restrict__ x,
        float* __restrict__ Yf) {
    __shared__ __bf16 As[64][32];
    __shared__ __bf16 Bs[128][32];
    const int t    = threadIdx.x;
    const int lane = t & 63, w = t >> 6;
    const int quad = lane >> 4, l15 = lane & 15;
    const int wm = w & 1, wn = w >> 1;
    const int bm = blockIdx.y * 64, bn = blockIdx.x * 128;

    const int ar = t >> 2, ac = (t & 3) * 8;    // A stager
    const int br = t >> 1, bc = (t & 1) * 16;   // B stager
    const int arow = bm + ar;

    v4f acc[2][4] = {};
    for (int k0 = 0; k0 < FEAT; k0 += 32) {
        {   // A: combine SPLIT partials -> bf16
            int h = (k0 + ac) >> 6;             // uniform over this thread's 8 cols
            float ls[SPLIT], tot = 0.f;
#pragma unroll
            for (int s = 0; s < SPLIT; s++) {
                ls[s] = lp[((size_t)s * HEADS + h) * N_TOK + arow];
                tot += ls[s];
            }
            float inv = 1.0f / tot;
            float a8[8] = {};
#pragma unroll
            for (int s = 0; s < SPLIT; s++) {
                v8bf p = *(const v8bf*)(Op + (size_t)s * XE + (size_t)arow * FEAT + k0 + ac);
                float wgt = ls[s] * inv;
#pragma unroll
                for (int j = 0; j < 8; j++) a8[j] += wgt * (float)p[j];
            }
            v8bf av;
#pragma unroll
            for (int j = 0; j < 8; j++) av[j] = (__bf16)a8[j];
            *(v8bf*)&As[ar][ac] = av;
        }
        {   // B: Wo f32 -> bf16
            const float* bp = Wo + (size_t)(bn + br) * FEAT + k0 + bc;
            float4 b0 = *(const float4*)bp,     b1 = *(const float4*)(bp + 4);
            float4 b2 = *(const float4*)(bp+8), b3 = *(const float4*)(bp + 12);
            v8bf v0, v1;
            v0[0]=(__bf16)b0.x; v0[1]=(__bf16)b0.y; v0[2]=(__bf16)b0.z; v0[3]=(__bf16)b0.w;
            v0[4]=(__bf16)b1.x; v0[5]=(__bf16)b1.y; v0[6]=(__bf16)b1.z; v0[7]=(__bf16)b1.w;
            v1[0]=(__bf16)b2.x; v1[1]=(__bf16)b2.y; v1[2]=(__bf16)b2.z; v1[3]=(__bf16)b2.w;
            v1[4]=(__bf16)b3.x; v1[5]=(__bf16)b3.y; v1[6]=(__bf16)b3.z; v1[7]=(__bf16)b3.w;
            *(v8bf*)&Bs[br][bc]     = v0;
            *(v8bf*)&Bs[br][bc + 8] = v1;
        }
        __syncthreads();
        v8bf a[2], b[4];
#pragma unroll
        for (int mi = 0; mi < 2; mi++) a[mi] = *(const v8bf*)&As[wm * 32 + mi * 16 + l15][quad * 8];
#pragma unroll
        for (int ni = 0; ni < 4; ni++) b[ni] = *(const v8bf*)&Bs[wn * 64 + ni * 16 + l15][quad * 8];
#pragma unroll
        for (int mi = 0; mi < 2; mi++)
#pragma unroll
            for (int ni = 0; ni < 4; ni++)
                acc[mi][ni] = __builtin_amdgcn_mfma_f32_16x16x32_bf16(a[mi], b[ni], acc[mi][ni], 0, 0, 0);
        __syncthreads();
    }
#pragma unroll
    for (int mi = 0; mi < 2; mi++)
#pragma unroll
        for (int ni = 0; ni < 4; ni++) {
            int col = bn + wn * 64 + ni * 16 + l15;
#pragma unroll
            for (int r = 0; r < 4; r++) {
                int row = bm + wm * 32 + mi * 16 + quad * 4 + r;
                Yf[(size_t)row * FEAT + col] = acc[mi][ni][r] + x[(size_t)row * FEAT + col];
            }
        }
}

// ---------------------------------------------------------------- layernorm
__global__ __launch_bounds__(256) void ln_kernel(
        const float* __restrict__ Y, const float* __restrict__ gamma,
        const float* __restrict__ beta, float* __restrict__ out) {
    __shared__ float sbuf[4];
    const int row = blockIdx.x, t = threadIdx.x;
    const float* y = Y + (size_t)row * FEAT;
    float v0 = y[t], v1 = y[t + 256], v2 = y[t + 512];
    float s = v0 + v1 + v2;
#pragma unroll
    for (int m = 32; m; m >>= 1) s += __shfl_xor(s, m);
    if ((t & 63) == 0) sbuf[t >> 6] = s;
    __syncthreads();
    float mean = (sbuf[0] + sbuf[1] + sbuf[2] + sbuf[3]) * (1.f / FEAT);
    __syncthreads();
    float d0 = v0 - mean, d1 = v1 - mean, d2 = v2 - mean;
    float q = d0 * d0 + d1 * d1 + d2 * d2;
#pragma unroll
    for (int m = 32; m; m >>= 1) q += __shfl_xor(q, m);
    if ((t & 63) == 0) sbuf[t >> 6] = q;
    __syncthreads();
    float var = (sbuf[0] + sbuf[1] + sbuf[2] + sbuf[3]) * (1.f / FEAT);
    float rs = rsqrtf(var + 1e-12f);
    float* o = out + (size_t)row * FEAT;
    o[t]       = d0 * rs * gamma[t]       + beta[t];
    o[t + 256] = d1 * rs * gamma[t + 256] + beta[t + 256];
    o[t + 512] = d2 * rs * gamma[t + 512] + beta[t + 512];
}

// ---------------------------------------------------------------- launch
extern "C" void kernel_launch(void* const* d_in, const int* in_sizes, int n_in,
                              void* d_out, int out_size, void* d_ws, size_t ws_size,
                              hipStream_t stream) {
    const float* x     = (const float*)d_in[0];
    const float* Wq    = (const float*)d_in[1];
    const float* Wk    = (const float*)d_in[2];
    const float* Wv    = (const float*)d_in[3];
    const float* Wo    = (const float*)d_in[4];
    const float* gamma = (const float*)d_in[5];
    const float* beta  = (const float*)d_in[6];
    float* out = (float*)d_out;

    char* ws = (char*)d_ws;
    size_t off = 0;
    auto alloc = [&](size_t bytes) -> void* {
        void* p = ws + off;
        off += (bytes + 255) & ~(size_t)255;
        return p;
    };
    __bf16* qk  = (__bf16*)alloc((size_t)N_TOK * QK_LD * 2);  // [Q'|K]; dead after attention
    __bf16* vtb = (__bf16*)alloc((size_t)FEAT * N_TOK * 2);   // V^T [768][2048]; dead after attention
    __bf16* Op  = (__bf16*)alloc(SPLIT * XE * 2);             // normalized split partials
    float*  lp  = (float*)alloc(SPLIT * HEADS * N_TOK * 4);
    float*  Yf  = (float*)ws;                                 // aliases qk (6.29 MB, exact fit)

    // 2304 output cols / 128 = 18 column-tiles (Round 6 bug: had 24 -> OOB on Wv)
    gemm_qkv<<<dim3((QK_LD + FEAT) / 128, N_TOK / 64), 256, 0, stream>>>(
        x, Wq, Wk, Wv, qk, vtb);

    attention<<<dim3(N_TOK / 128, HEADS, SPLIT), 256, 0, stream>>>(qk, vtb, Op, lp);

    gemm_out<<<dim3(FEAT / 128, N_TOK / 64), 256, 0, stream>>>(Op, lp, Wo, x, Yf);

    ln_kernel<<<N_TOK, 256, 0, stream>>>(Yf, gamma, beta, out);
}

// Round 8
// 151.246 us; speedup vs baseline: 1.4442x; 1.0463x over previous
//
#include <hip/hip_runtime.h>
#include <hip/hip_bf16.h>
#include <math.h>

#define N_TOK 2048
#define FEAT  768
#define HEADS 12
#define DHEAD 64
#define SPLIT 4
#define KV_PER (N_TOK / SPLIT)

typedef __bf16 v8bf __attribute__((ext_vector_type(8)));
typedef __bf16 v4bf __attribute__((ext_vector_type(4)));
typedef float  v4f  __attribute__((ext_vector_type(4)));

#define XE ((size_t)N_TOK * FEAT)   // 1572864
#define WE ((size_t)FEAT * FEAT)    //  589824
#define QK_LD 1536                  // [Q'|K] row stride

// fold (1/sqrt(64)) * log2(e) into Wq so softmax is a bare exp2
#define SCALE_FOLD 0.18033688011112042f

// async global->LDS, 16B/lane; LDS dest = wave-uniform base + lane*16 (m104)
__device__ __forceinline__ void gload16(const __bf16* g, __bf16* l) {
    __builtin_amdgcn_global_load_lds(
        (const __attribute__((address_space(1))) unsigned int*)g,
        (__attribute__((address_space(3))) unsigned int*)l, 16, 0, 0);
}

// ---------------------------------------------------------------- convert (1 launch)
// wqkv rows: [0,768) Wq*SCALE_FOLD, [768,1536) Wk, [1536,2304) Wv — contiguous, stride 768.
__global__ __launch_bounds__(256) void cvt_all(
        const float* __restrict__ x,  const float* __restrict__ Wq,
        const float* __restrict__ Wk, const float* __restrict__ Wv,
        const float* __restrict__ Wo,
        __bf16* __restrict__ xb, __bf16* __restrict__ wqkv, __bf16* __restrict__ wob) {
    size_t i = ((size_t)blockIdx.x * 256 + threadIdx.x) * 4;
    const float* src; __bf16* dst; size_t off; float scale = 1.f;
    if (i < XE)               { src = x;  dst = xb;          off = i; }
    else if (i < XE + WE)     { src = Wq; dst = wqkv;        off = i - XE; scale = SCALE_FOLD; }
    else if (i < XE + 2 * WE) { src = Wk; dst = wqkv + WE;   off = i - XE - WE; }
    else if (i < XE + 3 * WE) { src = Wv; dst = wqkv + 2*WE; off = i - XE - 2*WE; }
    else                      { src = Wo; dst = wob;         off = i - XE - 3*WE; }
    float4 v = *(const float4*)(src + off);
    v4bf o;
    o[0] = (__bf16)(v.x * scale); o[1] = (__bf16)(v.y * scale);
    o[2] = (__bf16)(v.z * scale); o[3] = (__bf16)(v.w * scale);
    *(v4bf*)(dst + off) = o;
}

// ---------------------------------------------------------------- fused QKV GEMM (bf16, gload16)
// C = xb . wqkv^T. 64x128 tile, BK=32. Grid (18, 32).
// QK cols (bn<1536) -> qk row-major stride 1536; V cols -> vt transposed [768][2048].
__global__ __launch_bounds__(256) void gemm_qkv(
        const __bf16* __restrict__ A, const __bf16* __restrict__ B,
        __bf16* __restrict__ qk, __bf16* __restrict__ vt) {
    __shared__ __bf16 As[64][32];
    __shared__ __bf16 Bs[128][32];
    const int t    = threadIdx.x;
    const int lane = t & 63, w = t >> 6;
    const int quad = lane >> 4, l15 = lane & 15;
    const int wm = w & 1, wn = w >> 1;
    const int bm = blockIdx.y * 64, bn = blockIdx.x * 128;
    const int srow = lane >> 2, scol = (lane & 3) * 8;   // lane -> 16B staging slot

    v4f acc[2][4] = {};
    for (int k0 = 0; k0 < FEAT; k0 += 32) {
        gload16(A + (size_t)(bm + w * 16 + srow) * FEAT + k0 + scol,      &As[w * 16][0]);
        gload16(B + (size_t)(bn + w * 32 + srow) * FEAT + k0 + scol,      &Bs[w * 32][0]);
        gload16(B + (size_t)(bn + w * 32 + 16 + srow) * FEAT + k0 + scol, &Bs[w * 32 + 16][0]);
        __syncthreads();
        v8bf a[2], b[4];
#pragma unroll
        for (int mi = 0; mi < 2; mi++) a[mi] = *(const v8bf*)&As[wm * 32 + mi * 16 + l15][quad * 8];
#pragma unroll
        for (int ni = 0; ni < 4; ni++) b[ni] = *(const v8bf*)&Bs[wn * 64 + ni * 16 + l15][quad * 8];
#pragma unroll
        for (int mi = 0; mi < 2; mi++)
#pragma unroll
            for (int ni = 0; ni < 4; ni++)
                acc[mi][ni] = __builtin_amdgcn_mfma_f32_16x16x32_bf16(a[mi], b[ni], acc[mi][ni], 0, 0, 0);
        __syncthreads();
    }
    if (bn < 2 * FEAT) {         // Q,K region
#pragma unroll
        for (int mi = 0; mi < 2; mi++)
#pragma unroll
            for (int ni = 0; ni < 4; ni++) {
                int col = bn + wn * 64 + ni * 16 + l15;
#pragma unroll
                for (int r = 0; r < 4; r++) {
                    int row = bm + wm * 32 + mi * 16 + quad * 4 + r;
                    qk[(size_t)row * QK_LD + col] = (__bf16)acc[mi][ni][r];
                }
            }
    } else {                     // V region: transposed packed store vt[col-1536][row]
#pragma unroll
        for (int mi = 0; mi < 2; mi++)
#pragma unroll
            for (int ni = 0; ni < 4; ni++) {
                int col = bn + wn * 64 + ni * 16 + l15 - 2 * FEAT;
                int row = bm + wm * 32 + mi * 16 + quad * 4;
                v4bf pk;
#pragma unroll
                for (int r = 0; r < 4; r++) pk[r] = (__bf16)acc[mi][ni][r];
                *(v4bf*)(vt + (size_t)col * N_TOK + row) = pk;
            }
    }
}

// ---------------------------------------------------------------- attention (unchanged from R7)
// K,V tiles staged via global_load_lds, shared across the block's 4 waves,
// double-buffered; XOR swizzle on global slot so frag ds_read_b128 is conflict-free.
__global__ __launch_bounds__(256, 3) void attention(
        const __bf16* __restrict__ QK, const __bf16* __restrict__ vt,
        __bf16* __restrict__ Opart, float* __restrict__ lpart) {
    __shared__ __bf16 KV[2][2][64][64];   // [buf][K/V][row][64]
    __shared__ __bf16 P[4][32][68];
    const int t    = threadIdx.x;
    const int lane = t & 63, w = t >> 6;
    const int quad = lane >> 4, l15 = lane & 15;
    const int h = blockIdx.y, s = blockIdx.z;
    const int q0 = blockIdx.x * 128 + w * 32;

    v8bf qf[2][2];
#pragma unroll
    for (int mh = 0; mh < 2; mh++) {
        const __bf16* qp = QK + (size_t)(q0 + mh * 16 + l15) * QK_LD + h * DHEAD + quad * 8;
        qf[mh][0] = *(const v8bf*)qp;
        qf[mh][1] = *(const v8bf*)(qp + 32);
    }
    const __bf16* kg = QK + FEAT + h * DHEAD;
    const __bf16* vg = vt + (size_t)(h * DHEAD) * N_TOK;

    v4f o_acc[2][4] = {};
    float lacc[2][4] = {{0.f,0.f,0.f,0.f},{0.f,0.f,0.f,0.f}};

    const int kvbeg = s * KV_PER;
    const int lr8 = lane >> 3;

    auto stage = [&](int b, int kv0) {
#pragma unroll
        for (int i = 0; i < 2; i++) {
            int row = w * 16 + i * 8 + lr8;
            int gs  = (lane & 7) ^ (row & 7);              // global-side swizzle
            gload16(kg + (size_t)(kv0 + row) * QK_LD + gs * 8, &KV[b][0][w * 16 + i * 8][0]);
            gload16(vg + (size_t)row * N_TOK + kv0 + gs * 8,   &KV[b][1][w * 16 + i * 8][0]);
        }
    };

    auto step = [&](int b) {
        v8bf kf[4][2];
#pragma unroll
        for (int nt = 0; nt < 4; nt++)
#pragma unroll
            for (int ks = 0; ks < 2; ks++)
                kf[nt][ks] = *(const v8bf*)&KV[b][0][nt * 16 + l15][((ks * 4 + quad) ^ (l15 & 7)) * 8];
        v4f sv[2][4];
#pragma unroll
        for (int mh = 0; mh < 2; mh++)
#pragma unroll
            for (int nt = 0; nt < 4; nt++) {
                v4f a = {};
                a = __builtin_amdgcn_mfma_f32_16x16x32_bf16(qf[mh][0], kf[nt][0], a, 0, 0, 0);
                a = __builtin_amdgcn_mfma_f32_16x16x32_bf16(qf[mh][1], kf[nt][1], a, 0, 0, 0);
                sv[mh][nt] = a;
            }
#pragma unroll
        for (int mh = 0; mh < 2; mh++)
#pragma unroll
            for (int r = 0; r < 4; r++) {
                float p0 = __builtin_amdgcn_exp2f(sv[mh][0][r]);
                float p1 = __builtin_amdgcn_exp2f(sv[mh][1][r]);
                float p2 = __builtin_amdgcn_exp2f(sv[mh][2][r]);
                float p3 = __builtin_amdgcn_exp2f(sv[mh][3][r]);
                lacc[mh][r] += (p0 + p1) + (p2 + p3);
                P[w][mh * 16 + quad * 4 + r][ 0 + l15] = (__bf16)p0;
                P[w][mh * 16 + quad * 4 + r][16 + l15] = (__bf16)p1;
                P[w][mh * 16 + quad * 4 + r][32 + l15] = (__bf16)p2;
                P[w][mh * 16 + quad * 4 + r][48 + l15] = (__bf16)p3;
            }
        v8bf vf[2][4];
#pragma unroll
        for (int ks = 0; ks < 2; ks++)
#pragma unroll
            for (int dt = 0; dt < 4; dt++)
                vf[ks][dt] = *(const v8bf*)&KV[b][1][dt * 16 + l15][((ks * 4 + quad) ^ (l15 & 7)) * 8];
#pragma unroll
        for (int mh = 0; mh < 2; mh++)
#pragma unroll
            for (int ks = 0; ks < 2; ks++) {
                v8bf pa = *(const v8bf*)&P[w][mh * 16 + l15][ks * 32 + quad * 8];
#pragma unroll
                for (int dt = 0; dt < 4; dt++)
                    o_acc[mh][dt] = __builtin_amdgcn_mfma_f32_16x16x32_bf16(pa, vf[ks][dt], o_acc[mh][dt], 0, 0, 0);
            }
    };

    stage(0, kvbeg);
    const int TILES = KV_PER / 64;     // 8
    for (int tt = 0; tt < TILES; tt++) {
        __syncthreads();
        if (tt + 1 < TILES) stage((tt + 1) & 1, kvbeg + (tt + 1) * 64);
        step(tt & 1);
    }

    __bf16* op = Opart + (size_t)s * XE;
#pragma unroll
    for (int mh = 0; mh < 2; mh++)
#pragma unroll
        for (int r = 0; r < 4; r++) {
            float l = lacc[mh][r];
            l += __shfl_xor(l, 1); l += __shfl_xor(l, 2);
            l += __shfl_xor(l, 4); l += __shfl_xor(l, 8);
            float linv = 1.0f / l;
            int row = q0 + mh * 16 + quad * 4 + r;
            if (l15 == 0) lpart[((size_t)s * HEADS + h) * N_TOK + row] = l;
#pragma unroll
            for (int dt = 0; dt < 4; dt++)
                op[(size_t)row * FEAT + h * DHEAD + dt * 16 + l15] = (__bf16)(o_acc[mh][dt][r] * linv);
        }
}

// ---------------------------------------------------------------- output proj (combine fused) + residual
// A-tile = weighted sum of SPLIT normalized partials (combine in stager).
// B = wob bf16 via gload16. 64x128 tile, BK=32. Yf = A.Wo^T + x (f32).
__global__ __launch_bounds__(256) void gemm_out(
        const __bf16* __restrict__ Op, const float* __restrict__ lp,
        const __bf16* __restrict__ Wo, const float* __restrict__ x,
        float* __restrict__ Yf) {
    __shared__ __bf16 As[64][32];
    __shared__ __bf16 Bs[128][32];
    const int t    = threadIdx.x;
    const int lane = t & 63, w = t >> 6;
    const int quad = lane >> 4, l15 = lane & 15;
    const int wm = w & 1, wn = w >> 1;
    const int bm = blockIdx.y * 64, bn = blockIdx.x * 128;
    const int srow = lane >> 2, scol = (lane & 3) * 8;

    const int ar = t >> 2, ac = (t & 3) * 8;    // A combine-stager
    const int arow = bm + ar;

    v4f acc[2][4] = {};
    for (int k0 = 0; k0 < FEAT; k0 += 32) {
        {   // A: combine SPLIT partials -> bf16
            int h = (k0 + ac) >> 6;             // uniform over this thread's 8 cols
            float ls[SPLIT], tot = 0.f;
#pragma unroll
            for (int s = 0; s < SPLIT; s++) {
                ls[s] = lp[((size_t)s * HEADS + h) * N_TOK + arow];
                tot += ls[s];
            }
            float inv = 1.0f / tot;
            float a8[8] = {};
#pragma unroll
            for (int s = 0; s < SPLIT; s++) {
                v8bf p = *(const v8bf*)(Op + (size_t)s * XE + (size_t)arow * FEAT + k0 + ac);
                float wgt = ls[s] * inv;
#pragma unroll
                for (int j = 0; j < 8; j++) a8[j] += wgt * (float)p[j];
            }
            v8bf av;
#pragma unroll
            for (int j = 0; j < 8; j++) av[j] = (__bf16)a8[j];
            *(v8bf*)&As[ar][ac] = av;
        }
        gload16(Wo + (size_t)(bn + w * 32 + srow) * FEAT + k0 + scol,      &Bs[w * 32][0]);
        gload16(Wo + (size_t)(bn + w * 32 + 16 + srow) * FEAT + k0 + scol, &Bs[w * 32 + 16][0]);
        __syncthreads();
        v8bf a[2], b[4];
#pragma unroll
        for (int mi = 0; mi < 2; mi++) a[mi] = *(const v8bf*)&As[wm * 32 + mi * 16 + l15][quad * 8];
#pragma unroll
        for (int ni = 0; ni < 4; ni++) b[ni] = *(const v8bf*)&Bs[wn * 64 + ni * 16 + l15][quad * 8];
#pragma unroll
        for (int mi = 0; mi < 2; mi++)
#pragma unroll
            for (int ni = 0; ni < 4; ni++)
                acc[mi][ni] = __builtin_amdgcn_mfma_f32_16x16x32_bf16(a[mi], b[ni], acc[mi][ni], 0, 0, 0);
        __syncthreads();
    }
#pragma unroll
    for (int mi = 0; mi < 2; mi++)
#pragma unroll
        for (int ni = 0; ni < 4; ni++) {
            int col = bn + wn * 64 + ni * 16 + l15;
#pragma unroll
            for (int r = 0; r < 4; r++) {
                int row = bm + wm * 32 + mi * 16 + quad * 4 + r;
                Yf[(size_t)row * FEAT + col] = acc[mi][ni][r] + x[(size_t)row * FEAT + col];
            }
        }
}

// ---------------------------------------------------------------- layernorm
__global__ __launch_bounds__(256) void ln_kernel(
        const float* __restrict__ Y, const float* __restrict__ gamma,
        const float* __restrict__ beta, float* __restrict__ out) {
    __shared__ float sbuf[4];
    const int row = blockIdx.x, t = threadIdx.x;
    const float* y = Y + (size_t)row * FEAT;
    float v0 = y[t], v1 = y[t + 256], v2 = y[t + 512];
    float s = v0 + v1 + v2;
#pragma unroll
    for (int m = 32; m; m >>= 1) s += __shfl_xor(s, m);
    if ((t & 63) == 0) sbuf[t >> 6] = s;
    __syncthreads();
    float mean = (sbuf[0] + sbuf[1] + sbuf[2] + sbuf[3]) * (1.f / FEAT);
    __syncthreads();
    float d0 = v0 - mean, d1 = v1 - mean, d2 = v2 - mean;
    float q = d0 * d0 + d1 * d1 + d2 * d2;
#pragma unroll
    for (int m = 32; m; m >>= 1) q += __shfl_xor(q, m);
    if ((t & 63) == 0) sbuf[t >> 6] = q;
    __syncthreads();
    float var = (sbuf[0] + sbuf[1] + sbuf[2] + sbuf[3]) * (1.f / FEAT);
    float rs = rsqrtf(var + 1e-12f);
    float* o = out + (size_t)row * FEAT;
    o[t]       = d0 * rs * gamma[t]       + beta[t];
    o[t + 256] = d1 * rs * gamma[t + 256] + beta[t + 256];
    o[t + 512] = d2 * rs * gamma[t + 512] + beta[t + 512];
}

// ---------------------------------------------------------------- launch
extern "C" void kernel_launch(void* const* d_in, const int* in_sizes, int n_in,
                              void* d_out, int out_size, void* d_ws, size_t ws_size,
                              hipStream_t stream) {
    const float* x     = (const float*)d_in[0];
    const float* Wq    = (const float*)d_in[1];
    const float* Wk    = (const float*)d_in[2];
    const float* Wv    = (const float*)d_in[3];
    const float* Wo    = (const float*)d_in[4];
    const float* gamma = (const float*)d_in[5];
    const float* beta  = (const float*)d_in[6];
    float* out = (float*)d_out;

    char* ws = (char*)d_ws;
    size_t off = 0;
    auto alloc = [&](size_t bytes) -> void* {
        void* p = ws + off;
        off += (bytes + 255) & ~(size_t)255;
        return p;
    };
    __bf16* xb   = (__bf16*)alloc(XE * 2);                    // dead after gemm_qkv
    __bf16* wqkv = (__bf16*)alloc(3 * WE * 2);                // dead after gemm_qkv
    __bf16* wob  = (__bf16*)alloc(WE * 2);
    __bf16* qk   = (__bf16*)alloc((size_t)N_TOK * QK_LD * 2); // [Q'|K]; dead after attention
    __bf16* vtb  = (__bf16*)alloc((size_t)FEAT * N_TOK * 2);  // V^T; dead after attention
    __bf16* Op   = (__bf16*)alloc(SPLIT * XE * 2);            // normalized split partials
    float*  lp   = (float*)alloc(SPLIT * HEADS * N_TOK * 4);
    float*  Yf   = (float*)ws;                                // aliases xb+wqkv (7.9 MB > 6.3 needed)

    cvt_all<<<(int)((XE + 4 * WE) / 4 / 256), 256, 0, stream>>>(x, Wq, Wk, Wv, Wo, xb, wqkv, wob);

    gemm_qkv<<<dim3((QK_LD + FEAT) / 128, N_TOK / 64), 256, 0, stream>>>(xb, wqkv, qk, vtb);

    attention<<<dim3(N_TOK / 128, HEADS, SPLIT), 256, 0, stream>>>(qk, vtb, Op, lp);

    gemm_out<<<dim3(FEAT / 128, N_TOK / 64), 256, 0, stream>>>(Op, lp, wob, x, Yf);

    ln_kernel<<<N_TOK, 256, 0, stream>>>(Yf, gamma, beta, out);
}

// Round 9
// 151.205 us; speedup vs baseline: 1.4446x; 1.0003x over previous
//
#include <hip/hip_runtime.h>
#include <hip/hip_bf16.h>
#include <math.h>

#define N_TOK 2048
#define FEAT  768
#define HEADS 12
#define DHEAD 64
#define SPLIT 4
#define KV_PER (N_TOK / SPLIT)

typedef __bf16 v8bf __attribute__((ext_vector_type(8)));
typedef __bf16 v4bf __attribute__((ext_vector_type(4)));
typedef float  v4f  __attribute__((ext_vector_type(4)));

#define XE ((size_t)N_TOK * FEAT)   // 1572864
#define WE ((size_t)FEAT * FEAT)    //  589824
#define QK_LD 1536                  // [Q'|K] row stride

// fold (1/sqrt(64)) * log2(e) into Wq so softmax is a bare exp2
#define SCALE_FOLD 0.18033688011112042f

// async global->LDS, 16B/lane; LDS dest = wave-uniform base + lane*16 (m104)
__device__ __forceinline__ void gload16(const __bf16* g, __bf16* l) {
    __builtin_amdgcn_global_load_lds(
        (const __attribute__((address_space(1))) unsigned int*)g,
        (__attribute__((address_space(3))) unsigned int*)l, 16, 0, 0);
}

// ---------------------------------------------------------------- convert (1 launch)
__global__ __launch_bounds__(256) void cvt_all(
        const float* __restrict__ x,  const float* __restrict__ Wq,
        const float* __restrict__ Wk, const float* __restrict__ Wv,
        const float* __restrict__ Wo,
        __bf16* __restrict__ xb, __bf16* __restrict__ wqkv, __bf16* __restrict__ wob) {
    size_t i = ((size_t)blockIdx.x * 256 + threadIdx.x) * 4;
    const float* src; __bf16* dst; size_t off; float scale = 1.f;
    if (i < XE)               { src = x;  dst = xb;          off = i; }
    else if (i < XE + WE)     { src = Wq; dst = wqkv;        off = i - XE; scale = SCALE_FOLD; }
    else if (i < XE + 2 * WE) { src = Wk; dst = wqkv + WE;   off = i - XE - WE; }
    else if (i < XE + 3 * WE) { src = Wv; dst = wqkv + 2*WE; off = i - XE - 2*WE; }
    else                      { src = Wo; dst = wob;         off = i - XE - 3*WE; }
    float4 v = *(const float4*)(src + off);
    v4bf o;
    o[0] = (__bf16)(v.x * scale); o[1] = (__bf16)(v.y * scale);
    o[2] = (__bf16)(v.z * scale); o[3] = (__bf16)(v.w * scale);
    *(v4bf*)(dst + off) = o;
}

// ---------------------------------------------------------------- fused QKV GEMM (bf16, gload16)
// 128x128 tile (m97 structure), BK=32. Grid (18, 16).
// QK cols (bn<1536) -> qk row-major stride 1536; V cols -> vt transposed [768][2048].
__global__ __launch_bounds__(256) void gemm_qkv(
        const __bf16* __restrict__ A, const __bf16* __restrict__ B,
        __bf16* __restrict__ qk, __bf16* __restrict__ vt) {
    __shared__ __bf16 As[128][32];
    __shared__ __bf16 Bs[128][32];
    const int t    = threadIdx.x;
    const int lane = t & 63, w = t >> 6;
    const int quad = lane >> 4, l15 = lane & 15;
    const int wm = w & 1, wn = w >> 1;
    const int bm = blockIdx.y * 128, bn = blockIdx.x * 128;
    const int srow = lane >> 2, scol = (lane & 3) * 8;   // lane -> 16B staging slot

    v4f acc[4][4] = {};
    for (int k0 = 0; k0 < FEAT; k0 += 32) {
        gload16(A + (size_t)(bm + w * 32 + srow) * FEAT + k0 + scol,      &As[w * 32][0]);
        gload16(A + (size_t)(bm + w * 32 + 16 + srow) * FEAT + k0 + scol, &As[w * 32 + 16][0]);
        gload16(B + (size_t)(bn + w * 32 + srow) * FEAT + k0 + scol,      &Bs[w * 32][0]);
        gload16(B + (size_t)(bn + w * 32 + 16 + srow) * FEAT + k0 + scol, &Bs[w * 32 + 16][0]);
        __syncthreads();
        v8bf a[4], b[4];
#pragma unroll
        for (int mi = 0; mi < 4; mi++) a[mi] = *(const v8bf*)&As[wm * 64 + mi * 16 + l15][quad * 8];
#pragma unroll
        for (int ni = 0; ni < 4; ni++) b[ni] = *(const v8bf*)&Bs[wn * 64 + ni * 16 + l15][quad * 8];
#pragma unroll
        for (int mi = 0; mi < 4; mi++)
#pragma unroll
            for (int ni = 0; ni < 4; ni++)
                acc[mi][ni] = __builtin_amdgcn_mfma_f32_16x16x32_bf16(a[mi], b[ni], acc[mi][ni], 0, 0, 0);
        __syncthreads();
    }
    if (bn < 2 * FEAT) {         // Q,K region
#pragma unroll
        for (int mi = 0; mi < 4; mi++)
#pragma unroll
            for (int ni = 0; ni < 4; ni++) {
                int col = bn + wn * 64 + ni * 16 + l15;
#pragma unroll
                for (int r = 0; r < 4; r++) {
                    int row = bm + wm * 64 + mi * 16 + quad * 4 + r;
                    qk[(size_t)row * QK_LD + col] = (__bf16)acc[mi][ni][r];
                }
            }
    } else {                     // V region: transposed packed store vt[col-1536][row]
#pragma unroll
        for (int mi = 0; mi < 4; mi++)
#pragma unroll
            for (int ni = 0; ni < 4; ni++) {
                int col = bn + wn * 64 + ni * 16 + l15 - 2 * FEAT;
                int row = bm + wm * 64 + mi * 16 + quad * 4;
                v4bf pk;
#pragma unroll
                for (int r = 0; r < 4; r++) pk[r] = (__bf16)acc[mi][ni][r];
                *(v4bf*)(vt + (size_t)col * N_TOK + row) = pk;
            }
    }
}

// ---------------------------------------------------------------- attention v5 (S^T formulation)
// Computes S^T = K Q'^T (C-layout: kv=quad*4+r, q=l15) so p-values are kv-contiguous:
// P^T packed b64 LDS writes; PV as O^T = V^T P^T (vf as A, P^T rows as B);
// epilogue packs 4 d-contiguous values per store. K,V LDS-staged + dbuf as in v4.
__global__ __launch_bounds__(256, 3) void attention(
        const __bf16* __restrict__ QK, const __bf16* __restrict__ vt,
        __bf16* __restrict__ Opart, float* __restrict__ lpart) {
    __shared__ __bf16 KV[2][2][64][64];   // [buf][K/V][row][64]
    __shared__ __bf16 PT[4][32][64];      // per-wave P^T: [w][q][kv], XOR-swizzled kv
    const int t    = threadIdx.x;
    const int lane = t & 63, w = t >> 6;
    const int quad = lane >> 4, l15 = lane & 15;
    const int h = blockIdx.y, s = blockIdx.z;
    const int q0 = blockIdx.x * 128 + w * 32;
    const int sw = (l15 & 7) * 8;         // P^T kv swizzle (bits 3-5 by q&7)

    v8bf qf[2][2];
#pragma unroll
    for (int qt = 0; qt < 2; qt++) {
        const __bf16* qp = QK + (size_t)(q0 + qt * 16 + l15) * QK_LD + h * DHEAD + quad * 8;
        qf[qt][0] = *(const v8bf*)qp;
        qf[qt][1] = *(const v8bf*)(qp + 32);
    }
    const __bf16* kg = QK + FEAT + h * DHEAD;
    const __bf16* vg = vt + (size_t)(h * DHEAD) * N_TOK;

    v4f o_acc[4][2] = {};                 // [dt][qt], C rows = d (quad*4+r), cols = q
    float lacc[2] = {0.f, 0.f};           // per-lane partial row-sums for q = qt*16+l15

    const int kvbeg = s * KV_PER;
    const int lr8 = lane >> 3;

    auto stage = [&](int b, int kv0) {
#pragma unroll
        for (int i = 0; i < 2; i++) {
            int row = w * 16 + i * 8 + lr8;
            int gs  = (lane & 7) ^ (row & 7);              // global-side swizzle
            gload16(kg + (size_t)(kv0 + row) * QK_LD + gs * 8, &KV[b][0][w * 16 + i * 8][0]);
            gload16(vg + (size_t)row * N_TOK + kv0 + gs * 8,   &KV[b][1][w * 16 + i * 8][0]);
        }
    };

    auto step = [&](int b) {
        // ---- K frags (A-operand now; same lane data as before)
        v8bf kf[4][2];
#pragma unroll
        for (int kvt = 0; kvt < 4; kvt++)
#pragma unroll
            for (int ks = 0; ks < 2; ks++)
                kf[kvt][ks] = *(const v8bf*)&KV[b][0][kvt * 16 + l15][((ks * 4 + quad) ^ (l15 & 7)) * 8];
        // ---- S^T = K Q'^T : D[kv][q]
        v4f sv[4][2];
#pragma unroll
        for (int kvt = 0; kvt < 4; kvt++)
#pragma unroll
            for (int qt = 0; qt < 2; qt++) {
                v4f a = {};
                a = __builtin_amdgcn_mfma_f32_16x16x32_bf16(kf[kvt][0], qf[qt][0], a, 0, 0, 0);
                a = __builtin_amdgcn_mfma_f32_16x16x32_bf16(kf[kvt][1], qf[qt][1], a, 0, 0, 0);
                sv[kvt][qt] = a;
            }
        // ---- p = 2^s; lane's 4 values are kv-contiguous -> one b64 LDS write each
#pragma unroll
        for (int kvt = 0; kvt < 4; kvt++)
#pragma unroll
            for (int qt = 0; qt < 2; qt++) {
                float p0 = __builtin_amdgcn_exp2f(sv[kvt][qt][0]);
                float p1 = __builtin_amdgcn_exp2f(sv[kvt][qt][1]);
                float p2 = __builtin_amdgcn_exp2f(sv[kvt][qt][2]);
                float p3 = __builtin_amdgcn_exp2f(sv[kvt][qt][3]);
                lacc[qt] += (p0 + p1) + (p2 + p3);
                v4bf pk;
                pk[0] = (__bf16)p0; pk[1] = (__bf16)p1; pk[2] = (__bf16)p2; pk[3] = (__bf16)p3;
                *(v4bf*)&PT[w][qt * 16 + l15][(kvt * 16 + quad * 4) ^ sw] = pk;
            }
        // ---- O^T += V^T P^T  (vf as A: D rows = d; P^T rows as B: D cols = q)
        v8bf vf[2][4];
#pragma unroll
        for (int ks = 0; ks < 2; ks++)
#pragma unroll
            for (int dt = 0; dt < 4; dt++)
                vf[ks][dt] = *(const v8bf*)&KV[b][1][dt * 16 + l15][((ks * 4 + quad) ^ (l15 & 7)) * 8];
        v8bf ptf[2][2];
#pragma unroll
        for (int ks = 0; ks < 2; ks++)
#pragma unroll
            for (int qt = 0; qt < 2; qt++)
                ptf[ks][qt] = *(const v8bf*)&PT[w][qt * 16 + l15][(ks * 32 + quad * 8) ^ sw];
#pragma unroll
        for (int dt = 0; dt < 4; dt++)
#pragma unroll
            for (int ks = 0; ks < 2; ks++)
#pragma unroll
                for (int qt = 0; qt < 2; qt++)
                    o_acc[dt][qt] = __builtin_amdgcn_mfma_f32_16x16x32_bf16(vf[ks][dt], ptf[ks][qt], o_acc[dt][qt], 0, 0, 0);
    };

    stage(0, kvbeg);
    const int TILES = KV_PER / 64;     // 8
    for (int tt = 0; tt < TILES; tt++) {
        __syncthreads();
        if (tt + 1 < TILES) stage((tt + 1) & 1, kvbeg + (tt + 1) * 64);
        step(tt & 1);
    }

    // ---- epilogue: l-reduce over quads (2 shfls), packed b64 global stores
    __bf16* op = Opart + (size_t)s * XE;
#pragma unroll
    for (int qt = 0; qt < 2; qt++) {
        float l = lacc[qt];
        l += __shfl_xor(l, 16); l += __shfl_xor(l, 32);   // sum the 4 quads (same q)
        float linv = 1.0f / l;
        int q = q0 + qt * 16 + l15;
        if (quad == 0) lpart[((size_t)s * HEADS + h) * N_TOK + q] = l;
#pragma unroll
        for (int dt = 0; dt < 4; dt++) {
            v4bf pk;
#pragma unroll
            for (int r = 0; r < 4; r++) pk[r] = (__bf16)(o_acc[dt][qt][r] * linv);
            *(v4bf*)(op + (size_t)q * FEAT + h * DHEAD + dt * 16 + quad * 4) = pk;
        }
    }
}

// ---------------------------------------------------------------- output proj (combine fused) + residual
__global__ __launch_bounds__(256) void gemm_out(
        const __bf16* __restrict__ Op, const float* __restrict__ lp,
        const __bf16* __restrict__ Wo, const float* __restrict__ x,
        float* __restrict__ Yf) {
    __shared__ __bf16 As[64][32];
    __shared__ __bf16 Bs[128][32];
    const int t    = threadIdx.x;
    const int lane = t & 63, w = t >> 6;
    const int quad = lane >> 4, l15 = lane & 15;
    const int wm = w & 1, wn = w >> 1;
    const int bm = blockIdx.y * 64, bn = blockIdx.x * 128;
    const int srow = lane >> 2, scol = (lane & 3) * 8;

    const int ar = t >> 2, ac = (t & 3) * 8;    // A combine-stager
    const int arow = bm + ar;

    v4f acc[2][4] = {};
    for (int k0 = 0; k0 < FEAT; k0 += 32) {
        {   // A: combine SPLIT partials -> bf16
            int h = (k0 + ac) >> 6;             // uniform over this thread's 8 cols
            float ls[SPLIT], tot = 0.f;
#pragma unroll
            for (int s = 0; s < SPLIT; s++) {
                ls[s] = lp[((size_t)s * HEADS + h) * N_TOK + arow];
                tot += ls[s];
            }
            float inv = 1.0f / tot;
            float a8[8] = {};
#pragma unroll
            for (int s = 0; s < SPLIT; s++) {
                v8bf p = *(const v8bf*)(Op + (size_t)s * XE + (size_t)arow * FEAT + k0 + ac);
                float wgt = ls[s] * inv;
#pragma unroll
                for (int j = 0; j < 8; j++) a8[j] += wgt * (float)p[j];
            }
            v8bf av;
#pragma unroll
            for (int j = 0; j < 8; j++) av[j] = (__bf16)a8[j];
            *(v8bf*)&As[ar][ac] = av;
        }
        gload16(Wo + (size_t)(bn + w * 32 + srow) * FEAT + k0 + scol,      &Bs[w * 32][0]);
        gload16(Wo + (size_t)(bn + w * 32 + 16 + srow) * FEAT + k0 + scol, &Bs[w * 32 + 16][0]);
        __syncthreads();
        v8bf a[2], b[4];
#pragma unroll
        for (int mi = 0; mi < 2; mi++) a[mi] = *(const v8bf*)&As[wm * 32 + mi * 16 + l15][quad * 8];
#pragma unroll
        for (int ni = 0; ni < 4; ni++) b[ni] = *(const v8bf*)&Bs[wn * 64 + ni * 16 + l15][quad * 8];
#pragma unroll
        for (int mi = 0; mi < 2; mi++)
#pragma unroll
            for (int ni = 0; ni < 4; ni++)
                acc[mi][ni] = __builtin_amdgcn_mfma_f32_16x16x32_bf16(a[mi], b[ni], acc[mi][ni], 0, 0, 0);
        __syncthreads();
    }
#pragma unroll
    for (int mi = 0; mi < 2; mi++)
#pragma unroll
        for (int ni = 0; ni < 4; ni++) {
            int col = bn + wn * 64 + ni * 16 + l15;
#pragma unroll
            for (int r = 0; r < 4; r++) {
                int row = bm + wm * 32 + mi * 16 + quad * 4 + r;
                Yf[(size_t)row * FEAT + col] = acc[mi][ni][r] + x[(size_t)row * FEAT + col];
            }
        }
}

// ---------------------------------------------------------------- layernorm
__global__ __launch_bounds__(256) void ln_kernel(
        const float* __restrict__ Y, const float* __restrict__ gamma,
        const float* __restrict__ beta, float* __restrict__ out) {
    __shared__ float sbuf[4];
    const int row = blockIdx.x, t = threadIdx.x;
    const float* y = Y + (size_t)row * FEAT;
    float v0 = y[t], v1 = y[t + 256], v2 = y[t + 512];
    float s = v0 + v1 + v2;
#pragma unroll
    for (int m = 32; m; m >>= 1) s += __shfl_xor(s, m);
    if ((t & 63) == 0) sbuf[t >> 6] = s;
    __syncthreads();
    float mean = (sbuf[0] + sbuf[1] + sbuf[2] + sbuf[3]) * (1.f / FEAT);
    __syncthreads();
    float d0 = v0 - mean, d1 = v1 - mean, d2 = v2 - mean;
    float q = d0 * d0 + d1 * d1 + d2 * d2;
#pragma unroll
    for (int m = 32; m; m >>= 1) q += __shfl_xor(q, m);
    if ((t & 63) == 0) sbuf[t >> 6] = q;
    __syncthreads();
    float var = (sbuf[0] + sbuf[1] + sbuf[2] + sbuf[3]) * (1.f / FEAT);
    float rs = rsqrtf(var + 1e-12f);
    float* o = out + (size_t)row * FEAT;
    o[t]       = d0 * rs * gamma[t]       + beta[t];
    o[t + 256] = d1 * rs * gamma[t + 256] + beta[t + 256];
    o[t + 512] = d2 * rs * gamma[t + 512] + beta[t + 512];
}

// ---------------------------------------------------------------- launch
extern "C" void kernel_launch(void* const* d_in, const int* in_sizes, int n_in,
                              void* d_out, int out_size, void* d_ws, size_t ws_size,
                              hipStream_t stream) {
    const float* x     = (const float*)d_in[0];
    const float* Wq    = (const float*)d_in[1];
    const float* Wk    = (const float*)d_in[2];
    const float* Wv    = (const float*)d_in[3];
    const float* Wo    = (const float*)d_in[4];
    const float* gamma = (const float*)d_in[5];
    const float* beta  = (const float*)d_in[6];
    float* out = (float*)d_out;

    char* ws = (char*)d_ws;
    size_t off = 0;
    auto alloc = [&](size_t bytes) -> void* {
        void* p = ws + off;
        off += (bytes + 255) & ~(size_t)255;
        return p;
    };
    __bf16* xb   = (__bf16*)alloc(XE * 2);                    // dead after gemm_qkv
    __bf16* wqkv = (__bf16*)alloc(3 * WE * 2);                // dead after gemm_qkv
    __bf16* wob  = (__bf16*)alloc(WE * 2);
    __bf16* qk   = (__bf16*)alloc((size_t)N_TOK * QK_LD * 2); // [Q'|K]; dead after attention
    __bf16* vtb  = (__bf16*)alloc((size_t)FEAT * N_TOK * 2);  // V^T; dead after attention
    __bf16* Op   = (__bf16*)alloc(SPLIT * XE * 2);            // normalized split partials
    float*  lp   = (float*)alloc(SPLIT * HEADS * N_TOK * 4);
    float*  Yf   = (float*)ws;                                // aliases xb+wqkv

    cvt_all<<<(int)((XE + 4 * WE) / 4 / 256), 256, 0, stream>>>(x, Wq, Wk, Wv, Wo, xb, wqkv, wob);

    gemm_qkv<<<dim3((QK_LD + FEAT) / 128, N_TOK / 128), 256, 0, stream>>>(xb, wqkv, qk, vtb);

    attention<<<dim3(N_TOK / 128, HEADS, SPLIT), 256, 0, stream>>>(qk, vtb, Op, lp);

    gemm_out<<<dim3(FEAT / 128, N_TOK / 64), 256, 0, stream>>>(Op, lp, wob, x, Yf);

    ln_kernel<<<N_TOK, 256, 0, stream>>>(Yf, gamma, beta, out);
}